// Round 1
// 4030.613 us; speedup vs baseline: 4.1532x; 4.1532x over previous
//
#include <hip/hip_runtime.h>

#define DD   1024
#define FF   4096
#define NTOK 8192
#define CAPC 4096

// ===================================================================
// Tiered implementation:
//   Tier A (ws >= 161 MB): full split-bf16 MFMA pipeline (3-term Markidis,
//           fp32-class accuracy; attention + MoE all on matrix cores).
//   Tier B (ws >= 113 MB): old fp32 attention + MFMA MoE.
//   Tier C (ws >=  49 MB): previous fp32 kernel verbatim.
// ===================================================================

typedef unsigned short u16;
typedef __attribute__((ext_vector_type(8))) short bfrag;   // 8 bf16 = 4 VGPR
typedef __attribute__((ext_vector_type(4))) float f4_t;

#define MFMA(a,b,c) __builtin_amdgcn_mfma_f32_16x16x32_bf16(a,b,c,0,0,0)

__device__ __forceinline__ u16 f2bf(float f){
  unsigned u = __float_as_uint(f);
  u += 0x7FFFu + ((u >> 16) & 1u);          // RNE
  return (u16)(u >> 16);
}
__device__ __forceinline__ float bf2f(u16 h){
  return __uint_as_float(((unsigned)h) << 16);
}
__device__ __forceinline__ void bsplit(float v, u16& h, u16& l){
  h = f2bf(v);
  l = f2bf(v - bf2f(h));
}

__device__ __forceinline__ float block_sum(float v, float* sh){
  #pragma unroll
  for (int off = 32; off > 0; off >>= 1) v += __shfl_down(v, off, 64);
  if ((threadIdx.x & 63) == 0) sh[threadIdx.x >> 6] = v;
  __syncthreads();
  float r = (sh[0] + sh[1]) + (sh[2] + sh[3]);
  __syncthreads();
  return r;
}
__device__ __forceinline__ float block_max(float v, float* sh){
  #pragma unroll
  for (int off = 32; off > 0; off >>= 1) v = fmaxf(v, __shfl_down(v, off, 64));
  if ((threadIdx.x & 63) == 0) sh[threadIdx.x >> 6] = v;
  __syncthreads();
  float r = fmaxf(fmaxf(sh[0], sh[1]), fmaxf(sh[2], sh[3]));
  __syncthreads();
  return r;
}

// ============== old fp32 tile-GEMM core (Tier B/C fallback) ==============
#define GEMM_CORE(KTILES, LOADA, LOADB) \
  __shared__ float As[64][17]; \
  __shared__ float Bs[16][65]; \
  float cc_[4][4] = {{0,0,0,0},{0,0,0,0},{0,0,0,0},{0,0,0,0}}; \
  const int tx = threadIdx.x & 15, ty = threadIdx.x >> 4; \
  for (int kt = 0; kt < (KTILES); ++kt){ \
    _Pragma("unroll") \
    for (int q_ = 0; q_ < 4; ++q_){ \
      int id_ = q_ * 256 + threadIdx.x; \
      { int r_ = id_ >> 4; int k_ = kt * 16 + (id_ & 15); As[r_][id_ & 15] = (LOADA); } \
      { int c_ = id_ & 63; int k_ = kt * 16 + (id_ >> 6); Bs[id_ >> 6][c_] = (LOADB); } \
    } \
    __syncthreads(); \
    _Pragma("unroll") \
    for (int kk_ = 0; kk_ < 16; ++kk_){ \
      float a_[4], b_[4]; \
      _Pragma("unroll") \
      for (int i_ = 0; i_ < 4; ++i_) a_[i_] = As[ty * 4 + i_][kk_]; \
      _Pragma("unroll") \
      for (int j_ = 0; j_ < 4; ++j_) b_[j_] = Bs[kk_][tx * 4 + j_]; \
      _Pragma("unroll") \
      for (int i_ = 0; i_ < 4; ++i_) \
        _Pragma("unroll") \
        for (int j_ = 0; j_ < 4; ++j_) cc_[i_][j_] += a_[i_] * b_[j_]; \
    } \
    __syncthreads(); \
  }

__device__ __forceinline__ float ln_elem(const float* __restrict__ x, const float* __restrict__ st,
    const float* __restrict__ g, const float* __restrict__ be, int t, int k){
  return (x[(size_t)t * DD + k] - st[2 * t]) * st[2 * t + 1] * g[k] + be[k];
}

__global__ __launch_bounds__(256) void ln_stats(const float* __restrict__ xb, float* __restrict__ stats)
{
  __shared__ float sh[4];
  int n = blockIdx.x, tid = threadIdx.x;
  float4 xv = *(const float4*)(xb + (size_t)n * DD + tid * 4);
  float v[4] = { xv.x, xv.y, xv.z, xv.w };
  float s = (v[0] + v[1]) + (v[2] + v[3]);
  s = block_sum(s, sh);
  float m = s * (1.0f / DD);
  float q = 0;
  #pragma unroll
  for (int i = 0; i < 4; ++i){ float d = v[i] - m; q += d * d; }
  q = block_sum(q, sh);
  if (tid == 0){
    stats[2 * n]     = m;
    stats[2 * n + 1] = 1.0f / sqrtf(q * (1.0f / DD) + 1e-5f);
  }
}

__global__ __launch_bounds__(256) void init_x1(const float* __restrict__ x,
    const float* __restrict__ bo, float* __restrict__ x1f)
{
  size_t i = (size_t)blockIdx.x * 1024 + threadIdx.x * 4;
  float4 xv = *(const float4*)(x + i);
  float4 bv = *(const float4*)(bo + (i & (DD - 1)));
  xv.x += bv.x; xv.y += bv.y; xv.z += bv.z; xv.w += bv.w;
  *(float4*)(x1f + i) = xv;
}

__global__ __launch_bounds__(256) void proj_gemm(const float* __restrict__ xin,
    const float* __restrict__ st, const float* __restrict__ g, const float* __restrict__ be,
    const float* __restrict__ w, const float* __restrict__ bias, float escale, int nofs,
    float* __restrict__ outq)
{
  const int n0 = blockIdx.x * 64, m0 = blockIdx.y * 64;
  GEMM_CORE(64,
    (ln_elem(xin, st, g, be, m0 + r_, k_)),
    (w[(size_t)k_ * DD + nofs + n0 + c_]))
  #pragma unroll
  for (int i = 0; i < 4; ++i){
    int t = m0 + ty * 4 + i, s = t >> 3, b = t & 7;
    #pragma unroll
    for (int j = 0; j < 4; ++j){
      int col = n0 + tx * 4 + j;
      outq[(size_t)b * 65536 + (size_t)s * 64 + col] = (cc_[i][j] + bias[nofs + col]) * escale;
    }
  }
}

__global__ __launch_bounds__(256) void score_gemm(const float* __restrict__ qc,
    const float* __restrict__ kc, float* __restrict__ sc, int pl0)
{
  const int n0 = blockIdx.x * 64, m0 = blockIdx.y * 64, pz = blockIdx.z;
  const size_t pb = (size_t)(pl0 + pz) * 65536;
  GEMM_CORE(4,
    (qc[pb + (size_t)(m0 + r_) * 64 + k_]),
    (kc[pb + (size_t)(n0 + c_) * 64 + k_]))
  #pragma unroll
  for (int i = 0; i < 4; ++i){
    int row = m0 + ty * 4 + i;
    #pragma unroll
    for (int j = 0; j < 4; ++j)
      sc[(size_t)pz * 1048576 + (size_t)row * 1024 + n0 + tx * 4 + j] = cc_[i][j];
  }
}

__global__ __launch_bounds__(256) void softmax_io(float* __restrict__ sc, const float* __restrict__ mask)
{
  __shared__ float sh[4];
  int row = blockIdx.x, tid = threadIdx.x;
  int q = row & 1023;
  float* srow = sc + (size_t)row * 1024;
  const float* mrow = mask + (size_t)q * 1024;
  int j0 = tid * 4;
  float4 sv = *(const float4*)(srow + j0);
  float4 mv = *(const float4*)(mrow + j0);
  float v[4] = { sv.x + mv.x, sv.y + mv.y, sv.z + mv.z, sv.w + mv.w };
  float mx = fmaxf(fmaxf(v[0], v[1]), fmaxf(v[2], v[3]));
  mx = block_max(mx, sh);
  float e[4]; float l = 0;
  #pragma unroll
  for (int i = 0; i < 4; ++i){ e[i] = expf(v[i] - mx); l += e[i]; }
  l = block_sum(l, sh);
  float inv = 1.0f / l;
  #pragma unroll
  for (int i = 0; i < 4; ++i) srow[j0 + i] = e[i] * inv;
}

__global__ __launch_bounds__(256) void pv_gemm(const float* __restrict__ sc,
    const float* __restrict__ vc, float* __restrict__ o_h, int pl0)
{
  const int n0 = blockIdx.x * 64, m0 = blockIdx.y * 64, pz = blockIdx.z;
  const size_t pb = (size_t)(pl0 + pz) * 65536;
  GEMM_CORE(64,
    (sc[(size_t)pz * 1048576 + (size_t)(m0 + r_) * 1024 + k_]),
    (vc[pb + (size_t)k_ * 64 + n0 + c_]))
  int b = pl0 + pz;
  #pragma unroll
  for (int i = 0; i < 4; ++i){
    int s = m0 + ty * 4 + i;
    #pragma unroll
    for (int j = 0; j < 4; ++j)
      o_h[(size_t)b * 65536 + (size_t)s * 64 + n0 + tx * 4 + j] = cc_[i][j];
  }
}

__global__ __launch_bounds__(256) void oproj_acc(const float* __restrict__ o_h,
    const float* __restrict__ wo, int h, float* __restrict__ x1f)
{
  const int n0 = blockIdx.x * 64, m0 = blockIdx.y * 64;
  GEMM_CORE(4,
    (o_h[(size_t)((m0 + r_) & 7) * 65536 + (size_t)((m0 + r_) >> 3) * 64 + k_]),
    (wo[(size_t)(h * 64 + k_) * DD + n0 + c_]))
  #pragma unroll
  for (int i = 0; i < 4; ++i){
    size_t row = m0 + ty * 4 + i;
    #pragma unroll
    for (int j = 0; j < 4; ++j){
      size_t o = row * DD + n0 + tx * 4 + j;
      x1f[o] += cc_[i][j];
    }
  }
}

__global__ __launch_bounds__(256) void logits_gemm(const float* __restrict__ x1f,
    const float* __restrict__ st2, const float* __restrict__ g2, const float* __restrict__ be2,
    const float* __restrict__ gw, float* __restrict__ logits)
{
  int n = blockIdx.x * 4 + (threadIdx.x >> 6);
  int l = threadIdx.x & 63;
  float m = st2[2 * n], rs = st2[2 * n + 1];
  float acc[8] = {0,0,0,0,0,0,0,0};
  for (int i = 0; i < 16; ++i){
    int d = i * 64 + l;
    float t = (x1f[(size_t)n * DD + d] - m) * rs * g2[d] + be2[d];
    const float* gr = gw + (size_t)d * 8;
    #pragma unroll
    for (int e = 0; e < 8; ++e) acc[e] += t * gr[e];
  }
  #pragma unroll
  for (int e = 0; e < 8; ++e){
    #pragma unroll
    for (int off = 32; off > 0; off >>= 1) acc[e] += __shfl_down(acc[e], off, 64);
  }
  if (l == 0){
    #pragma unroll
    for (int e = 0; e < 8; ++e) logits[(size_t)n * 8 + e] = acc[e];
  }
}

__global__ void routing_kernel(const float* __restrict__ logits, float* __restrict__ gval,
    int* __restrict__ src, int* __restrict__ cnt, float* __restrict__ sums)
{
  int n = blockIdx.x * 256 + threadIdx.x;
  if (n >= NTOK) return;
  const float* L = logits + (size_t)n * 8;
  float l[8];
  #pragma unroll
  for (int e = 0; e < 8; ++e) l[e] = L[e];
  float best = l[0]; int be = 0;
  #pragma unroll
  for (int e = 1; e < 8; ++e) if (l[e] > best){ best = l[e]; be = e; }
  float g[8], es = 0;
  #pragma unroll
  for (int e = 0; e < 8; ++e){ g[e] = expf(l[e] - best); es += g[e]; }
  #pragma unroll
  for (int e = 0; e < 8; ++e) atomicAdd(&sums[e], g[e] / es);
  float gv = g[be] / es;
  int r = atomicAdd(&cnt[be], 1);
  bool keep = r < CAPC;
  gval[n] = keep ? gv : 0.0f;
  if (keep) src[be * CAPC + r] = n;
}

__global__ void laux_kernel(const float* __restrict__ sums, const int* __restrict__ cnt,
    float* __restrict__ outp)
{
  if (threadIdx.x == 0 && blockIdx.x == 0){
    float la = 0;
    for (int e = 0; e < 8; ++e) la += (sums[e] * (1.0f / NTOK)) * ((float)cnt[e] * (1.0f / NTOK));
    outp[0] = la * 8.0f;
  }
}

__global__ __launch_bounds__(256) void copy_x1(const float* __restrict__ x1f, float* __restrict__ outp)
{
  size_t i = (size_t)blockIdx.x * 1024 + threadIdx.x * 4;
  *(float4*)(outp + i) = *(const float4*)(x1f + i);
}

__global__ __launch_bounds__(256) void moe1_gemm(const float* __restrict__ x1f,
    const float* __restrict__ st2, const float* __restrict__ g2, const float* __restrict__ be2,
    const int* __restrict__ srcp, const int* __restrict__ cntp, int moff,
    const float* __restrict__ w1e, const float* __restrict__ b1e, float* __restrict__ hbuf)
{
  int c = *cntp; if (c > CAPC) c = CAPC; c -= moff; if (c < 0) c = 0;
  const int count = c < 1024 ? c : 1024;
  const int n0 = blockIdx.x * 64, m0 = blockIdx.y * 64;
  if (m0 >= count) return;
  GEMM_CORE(64,
    (ln_elem(x1f, st2, g2, be2, ((m0 + r_) < count ? srcp[m0 + r_] : 0), k_)),
    (w1e[(size_t)k_ * FF + n0 + c_]))
  #pragma unroll
  for (int i = 0; i < 4; ++i){
    int slot = m0 + ty * 4 + i;
    if (slot >= count) continue;
    #pragma unroll
    for (int j = 0; j < 4; ++j){
      int col = n0 + tx * 4 + j;
      hbuf[(size_t)slot * FF + col] = fmaxf(cc_[i][j] + b1e[col], 0.0f);
    }
  }
}

__global__ __launch_bounds__(256) void moe2_gemm(const float* __restrict__ hbuf,
    const float* __restrict__ w2e, const float* __restrict__ b2e, const int* __restrict__ srcp,
    const int* __restrict__ cntp, int moff, const float* __restrict__ gval,
    float* __restrict__ outp)
{
  int c = *cntp; if (c > CAPC) c = CAPC; c -= moff; if (c < 0) c = 0;
  const int count = c < 1024 ? c : 1024;
  const int n0 = blockIdx.x * 64, m0 = blockIdx.y * 64;
  if (m0 >= count) return;
  GEMM_CORE(256,
    (hbuf[(size_t)(m0 + r_) * FF + k_]),
    (w2e[(size_t)k_ * DD + n0 + c_]))
  #pragma unroll
  for (int i = 0; i < 4; ++i){
    int slot = m0 + ty * 4 + i;
    if (slot >= count) continue;
    int t = srcp[slot];
    float gv = gval[t];
    #pragma unroll
    for (int j = 0; j < 4; ++j){
      int col = n0 + tx * 4 + j;
      size_t o = (size_t)t * DD + col;
      outp[o] += gv * (cc_[i][j] + b2e[col]);
    }
  }
}

__global__ void zerofill_kernel(float* o, int nelem){
  int i = blockIdx.x * 256 + threadIdx.x;
  if (i < nelem) o[i] = 0.0f;
}

// ===================================================================
// split-bf16 MFMA GEMM core.  C = A * B^T  (A: [M][lda], B^T rows: [N][ldb],
// both as hi/lo bf16 planes).  BM=128, BN=128 or 64, BK=32, 256 thr = 4 waves
// (2x2), per-wave 64 x (BN/2), 4x(BN/32) frags of 16x16, 3 MFMA per frag pair.
// Reg-staged single-buffer with next-tile prefetch.
// ===================================================================
template<int BN, bool GATHER>
__device__ __forceinline__ void gemm_core(
    const u16* __restrict__ Ah, const u16* __restrict__ Al, int lda,
    const u16* __restrict__ Bh, const u16* __restrict__ Bl, int ldb,
    int m0, int n0, int K, const int* __restrict__ srcp, int count,
    f4_t (&acc)[4][BN / 32])
{
  constexpr int NJ = BN / 32;
  __shared__ u16 AsH[4096], AsL[4096], BsH[BN * 32], BsL[BN * 32];
  const int tid = threadIdx.x;

  // A staging: thread -> tile row tid>>1, 16 elems at (tid&1)*16
  const int ar = tid >> 1;
  long arow;
  if constexpr (GATHER){
    int r = m0 + ar; if (r >= count) r = (count > 0) ? count - 1 : 0;
    arow = srcp[r];
  } else {
    arow = m0 + ar;
  }
  const size_t abase = (size_t)arow * lda + (size_t)((tid & 1) * 16);

  // B staging
  int br, boff;
  if constexpr (BN == 128){ br = tid >> 1; boff = (tid & 1) * 16; }
  else                    { br = tid >> 2; boff = (tid & 3) * 8; }
  const size_t bbase = (size_t)(n0 + br) * ldb + boff;

  u16* aw_h = &AsH[ar * 32 + (tid & 1) * 16];
  u16* aw_l = &AsL[ar * 32 + (tid & 1) * 16];
  u16* bw_h = &BsH[br * 32 + boff];
  u16* bw_l = &BsL[br * 32 + boff];

  uint4 ra_h0, ra_h1, ra_l0, ra_l1, rb_h0, rb_h1, rb_l0, rb_l1;
  {
    ra_h0 = *(const uint4*)(Ah + abase);     ra_h1 = *(const uint4*)(Ah + abase + 8);
    ra_l0 = *(const uint4*)(Al + abase);     ra_l1 = *(const uint4*)(Al + abase + 8);
    if constexpr (BN == 128){
      rb_h0 = *(const uint4*)(Bh + bbase);   rb_h1 = *(const uint4*)(Bh + bbase + 8);
      rb_l0 = *(const uint4*)(Bl + bbase);   rb_l1 = *(const uint4*)(Bl + bbase + 8);
    } else {
      rb_h0 = *(const uint4*)(Bh + bbase);   rb_l0 = *(const uint4*)(Bl + bbase);
    }
  }

  const int KT = K >> 5;
  const int lane = tid & 63, wv = tid >> 6;
  const int wr = wv >> 1, wc = wv & 1;
  const int fr = lane & 15, fk = (lane >> 4) * 8;

  for (int kt = 0; kt < KT; ++kt){
    __syncthreads();                           // prev compute done, LDS free
    *(uint4*)(aw_h) = ra_h0; *(uint4*)(aw_h + 8) = ra_h1;
    *(uint4*)(aw_l) = ra_l0; *(uint4*)(aw_l + 8) = ra_l1;
    if constexpr (BN == 128){
      *(uint4*)(bw_h) = rb_h0; *(uint4*)(bw_h + 8) = rb_h1;
      *(uint4*)(bw_l) = rb_l0; *(uint4*)(bw_l + 8) = rb_l1;
    } else {
      *(uint4*)(bw_h) = rb_h0; *(uint4*)(bw_l) = rb_l0;
    }
    __syncthreads();
    if (kt + 1 < KT){                          // prefetch next K tile
      const size_t a = abase + (size_t)(kt + 1) * 32;
      const size_t b = bbase + (size_t)(kt + 1) * 32;
      ra_h0 = *(const uint4*)(Ah + a);   ra_h1 = *(const uint4*)(Ah + a + 8);
      ra_l0 = *(const uint4*)(Al + a);   ra_l1 = *(const uint4*)(Al + a + 8);
      if constexpr (BN == 128){
        rb_h0 = *(const uint4*)(Bh + b); rb_h1 = *(const uint4*)(Bh + b + 8);
        rb_l0 = *(const uint4*)(Bl + b); rb_l1 = *(const uint4*)(Bl + b + 8);
      } else {
        rb_h0 = *(const uint4*)(Bh + b); rb_l0 = *(const uint4*)(Bl + b);
      }
    }
    bfrag a_h[4], a_l[4];
    #pragma unroll
    for (int mi = 0; mi < 4; ++mi){
      int r = wr * 64 + mi * 16 + fr;
      a_h[mi] = *(const bfrag*)&AsH[r * 32 + fk];
      a_l[mi] = *(const bfrag*)&AsL[r * 32 + fk];
    }
    #pragma unroll
    for (int nj = 0; nj < NJ; ++nj){
      int c = wc * (BN / 2) + nj * 16 + fr;
      bfrag b_h = *(const bfrag*)&BsH[c * 32 + fk];
      bfrag b_l = *(const bfrag*)&BsL[c * 32 + fk];
      #pragma unroll
      for (int mi = 0; mi < 4; ++mi){
        acc[mi][nj] = MFMA(a_h[mi], b_h, acc[mi][nj]);
        acc[mi][nj] = MFMA(a_h[mi], b_l, acc[mi][nj]);
        acc[mi][nj] = MFMA(a_l[mi], b_h, acc[mi][nj]);
      }
    }
  }
}

#define EPI_COORDS(BNv) \
  const int lane_ = threadIdx.x & 63, wid_ = threadIdx.x >> 6; \
  const int er0 = (wid_ >> 1) * 64 + ((lane_ >> 4) << 2); \
  const int ec0 = (wid_ & 1) * ((BNv) / 2) + (lane_ & 15);

// ---------- helper kernels (split conversion) ----------

// LN + split of a fp32 [8192][1024] matrix into bf16 hi/lo planes
__global__ __launch_bounds__(256) void k_ln_split(const float* __restrict__ xb,
    const float* __restrict__ st, const float* __restrict__ g, const float* __restrict__ be,
    u16* __restrict__ oh, u16* __restrict__ ol)
{
  int n = blockIdx.x, j = threadIdx.x * 4;
  float m = st[2 * n], rs = st[2 * n + 1];
  float4 xv = *(const float4*)(xb + (size_t)n * DD + j);
  float4 gv = *(const float4*)(g + j);
  float4 bv = *(const float4*)(be + j);
  float t0 = (xv.x - m) * rs * gv.x + bv.x;
  float t1 = (xv.y - m) * rs * gv.y + bv.y;
  float t2 = (xv.z - m) * rs * gv.z + bv.z;
  float t3 = (xv.w - m) * rs * gv.w + bv.w;
  ushort4 hv, lv;
  bsplit(t0, hv.x, lv.x); bsplit(t1, hv.y, lv.y);
  bsplit(t2, hv.z, lv.z); bsplit(t3, hv.w, lv.w);
  *(ushort4*)(oh + (size_t)n * DD + j) = hv;
  *(ushort4*)(ol + (size_t)n * DD + j) = lv;
}

// fp32 W[K][ld] -> transposed split planes [N][ldo] (B^T layout for the GEMM)
__global__ __launch_bounds__(256) void k_split_T(const float* __restrict__ w, int ld,
    u16* __restrict__ th, u16* __restrict__ tl, int ldo)
{
  __shared__ float T[64][65];
  int n0 = blockIdx.x * 64, k0 = blockIdx.y * 64;
  int tx = threadIdx.x & 63, ty = threadIdx.x >> 6;
  #pragma unroll
  for (int r = 0; r < 16; ++r)
    T[ty * 16 + r][tx] = w[(size_t)(k0 + ty * 16 + r) * ld + n0 + tx];
  __syncthreads();
  #pragma unroll
  for (int r = 0; r < 16; ++r){
    int n = ty * 16 + r;
    float v = T[tx][n];
    u16 h, l; bsplit(v, h, l);
    size_t o = (size_t)(n0 + n) * ldo + k0 + tx;
    th[o] = h; tl[o] = l;
  }
}

// bf16 planes [pair][1024][64] -> [pair][64][1024]  (V -> V^T)
__global__ __launch_bounds__(256) void k_transpose_bf(const u16* __restrict__ vh,
    const u16* __restrict__ vl, u16* __restrict__ vTh, u16* __restrict__ vTl)
{
  __shared__ u16 T[64][65];
  const u16* src = blockIdx.y ? vl : vh;
  u16* dst = blockIdx.y ? vTl : vTh;
  int pair = blockIdx.z, s0 = blockIdx.x * 64;
  src += (size_t)pair * 65536; dst += (size_t)pair * 65536;
  int tx = threadIdx.x & 63, ty = threadIdx.x >> 6;
  #pragma unroll
  for (int r = 0; r < 16; ++r)
    T[ty * 16 + r][tx] = src[(size_t)(s0 + ty * 16 + r) * 64 + tx];
  __syncthreads();
  #pragma unroll
  for (int r = 0; r < 16; ++r){
    int hd = ty * 16 + r;
    dst[(size_t)hd * 1024 + s0 + tx] = T[tx][hd];
  }
}

// softmax over sc rows (4-pair chunk) -> split bf16 P planes
__global__ __launch_bounds__(256) void k_softmax_split(const float* __restrict__ sc,
    const float* __restrict__ mask, u16* __restrict__ ph, u16* __restrict__ pl)
{
  __shared__ float sh[4];
  int row = blockIdx.x, tid = threadIdx.x;
  int q = row & 1023;
  const float* srow = sc + (size_t)row * 1024;
  const float* mrow = mask + (size_t)q * 1024;
  int j0 = tid * 4;
  float4 sv = *(const float4*)(srow + j0);
  float4 mv = *(const float4*)(mrow + j0);
  float v[4] = { sv.x + mv.x, sv.y + mv.y, sv.z + mv.z, sv.w + mv.w };
  float mx = fmaxf(fmaxf(v[0], v[1]), fmaxf(v[2], v[3]));
  mx = block_max(mx, sh);
  float e[4]; float l = 0;
  #pragma unroll
  for (int i = 0; i < 4; ++i){ e[i] = expf(v[i] - mx); l += e[i]; }
  l = block_sum(l, sh);
  float inv = 1.0f / l;
  ushort4 hv, lv;
  float p0 = e[0] * inv, p1 = e[1] * inv, p2 = e[2] * inv, p3 = e[3] * inv;
  bsplit(p0, hv.x, lv.x); bsplit(p1, hv.y, lv.y);
  bsplit(p2, hv.z, lv.z); bsplit(p3, hv.w, lv.w);
  *(ushort4*)(ph + (size_t)row * 1024 + j0) = hv;
  *(ushort4*)(pl + (size_t)row * 1024 + j0) = lv;
}

// ---------- MFMA GEMM wrappers ----------

// QKV projection: [8192][1024] x W^T -> per-(b,h) planes [pair=b*16+h][1024][64]
__global__ __launch_bounds__(256) void k_proj(const u16* __restrict__ xh, const u16* __restrict__ xl,
    const u16* __restrict__ wTh, const u16* __restrict__ wTl,
    const float* __restrict__ bias, float scale,
    u16* __restrict__ oh, u16* __restrict__ ol)
{
  const f4_t fz = {0.f,0.f,0.f,0.f};
  f4_t acc[4][4];
  #pragma unroll
  for (int i = 0; i < 4; ++i){ acc[i][0]=fz; acc[i][1]=fz; acc[i][2]=fz; acc[i][3]=fz; }
  int m0 = blockIdx.y * 128, n0 = blockIdx.x * 128;
  gemm_core<128,false>(xh, xl, 1024, wTh, wTl, 1024, m0, n0, 1024, nullptr, 0, acc);
  EPI_COORDS(128)
  #pragma unroll
  for (int mi = 0; mi < 4; ++mi){
    #pragma unroll
    for (int i = 0; i < 4; ++i){
      int t = m0 + er0 + mi * 16 + i;
      int s = t >> 3, b = t & 7;
      #pragma unroll
      for (int nj = 0; nj < 4; ++nj){
        int cc = n0 + ec0 + nj * 16;
        float v = (acc[mi][nj][i] + bias[cc]) * scale;
        u16 hv, lv; bsplit(v, hv, lv);
        size_t o = (size_t)(b * 16 + (cc >> 6)) * 65536 + (size_t)s * 64 + (cc & 63);
        oh[o] = hv; ol[o] = lv;
      }
    }
  }
}

// scores: per pair, Q[1024][64] x K^T -> fp32 sc chunk [4][1024][1024]
__global__ __launch_bounds__(256) void k_scores(const u16* __restrict__ qh, const u16* __restrict__ ql,
    const u16* __restrict__ kh, const u16* __restrict__ kl, float* __restrict__ sc, int pl0)
{
  const f4_t fz = {0.f,0.f,0.f,0.f};
  f4_t acc[4][4];
  #pragma unroll
  for (int i = 0; i < 4; ++i){ acc[i][0]=fz; acc[i][1]=fz; acc[i][2]=fz; acc[i][3]=fz; }
  int zi = blockIdx.z;
  size_t pb = (size_t)(pl0 + zi) * 65536;
  int m0 = blockIdx.y * 128, n0 = blockIdx.x * 128;
  gemm_core<128,false>(qh + pb, ql + pb, 64, kh + pb, kl + pb, 64, m0, n0, 64, nullptr, 0, acc);
  float* scp = sc + ((size_t)zi << 20);
  EPI_COORDS(128)
  #pragma unroll
  for (int mi = 0; mi < 4; ++mi)
    #pragma unroll
    for (int i = 0; i < 4; ++i){
      int row = m0 + er0 + mi * 16 + i;
      #pragma unroll
      for (int nj = 0; nj < 4; ++nj)
        scp[(size_t)row * 1024 + n0 + ec0 + nj * 16] = acc[mi][nj][i];
    }
}

// PV: P[1024][1024] x V^T[64][1024] -> o planes [t][1024] (split store)
__global__ __launch_bounds__(256) void k_pv(const u16* __restrict__ ph, const u16* __restrict__ pl,
    const u16* __restrict__ vTh, const u16* __restrict__ vTl,
    u16* __restrict__ oh, u16* __restrict__ ol, int pl0)
{
  const f4_t fz = {0.f,0.f,0.f,0.f};
  f4_t acc[4][2];
  #pragma unroll
  for (int i = 0; i < 4; ++i){ acc[i][0]=fz; acc[i][1]=fz; }
  int zi = blockIdx.z;
  int pair = pl0 + zi;
  int m0 = blockIdx.y * 128;
  gemm_core<64,false>(ph + ((size_t)zi << 20), pl + ((size_t)zi << 20), 1024,
                      vTh + (size_t)pair * 65536, vTl + (size_t)pair * 65536, 1024,
                      m0, 0, 1024, nullptr, 0, acc);
  int b = pair >> 4, hh = pair & 15;
  EPI_COORDS(64)
  #pragma unroll
  for (int mi = 0; mi < 4; ++mi)
    #pragma unroll
    for (int i = 0; i < 4; ++i){
      int s = m0 + er0 + mi * 16 + i;
      size_t t = (size_t)(s * 8 + b);
      #pragma unroll
      for (int nj = 0; nj < 2; ++nj){
        int cl = ec0 + nj * 16;
        u16 hv, lv; bsplit(acc[mi][nj][i], hv, lv);
        size_t o = t * 1024 + hh * 64 + cl;
        oh[o] = hv; ol[o] = lv;
      }
    }
}

// O projection: o[8192][1024] x wo^T -> out = x + bo + acc   (out becomes x1)
__global__ __launch_bounds__(256) void k_oproj(const u16* __restrict__ oh, const u16* __restrict__ ol,
    const u16* __restrict__ wTh, const u16* __restrict__ wTl,
    const float* __restrict__ xin, const float* __restrict__ bo, float* __restrict__ outp)
{
  const f4_t fz = {0.f,0.f,0.f,0.f};
  f4_t acc[4][4];
  #pragma unroll
  for (int i = 0; i < 4; ++i){ acc[i][0]=fz; acc[i][1]=fz; acc[i][2]=fz; acc[i][3]=fz; }
  int m0 = blockIdx.y * 128, n0 = blockIdx.x * 128;
  gemm_core<128,false>(oh, ol, 1024, wTh, wTl, 1024, m0, n0, 1024, nullptr, 0, acc);
  EPI_COORDS(128)
  #pragma unroll
  for (int mi = 0; mi < 4; ++mi)
    #pragma unroll
    for (int i = 0; i < 4; ++i){
      size_t row = m0 + er0 + mi * 16 + i;
      #pragma unroll
      for (int nj = 0; nj < 4; ++nj){
        int cc = n0 + ec0 + nj * 16;
        size_t o = row * DD + cc;
        outp[o] = xin[o] + bo[cc] + acc[mi][nj][i];
      }
    }
}

// MoE GEMM1: gathered LN2 tokens x w1e^T -> relu -> split h planes
__global__ __launch_bounds__(256) void k_moe1(const u16* __restrict__ th, const u16* __restrict__ tl,
    const u16* __restrict__ w1Th, const u16* __restrict__ w1Tl, const float* __restrict__ b1e,
    const int* __restrict__ srcp, const int* __restrict__ cntp, int moff, int mcap,
    u16* __restrict__ hh, u16* __restrict__ hl)
{
  int c = *cntp; if (c > CAPC) c = CAPC; c -= moff; if (c < 0) c = 0; if (c > mcap) c = mcap;
  const int count = c;
  int m0 = blockIdx.y * 128, n0 = blockIdx.x * 128;
  if (m0 >= count) return;
  const f4_t fz = {0.f,0.f,0.f,0.f};
  f4_t acc[4][4];
  #pragma unroll
  for (int i = 0; i < 4; ++i){ acc[i][0]=fz; acc[i][1]=fz; acc[i][2]=fz; acc[i][3]=fz; }
  gemm_core<128,true>(th, tl, 1024, w1Th, w1Tl, 1024, m0, n0, 1024, srcp, count, acc);
  EPI_COORDS(128)
  #pragma unroll
  for (int mi = 0; mi < 4; ++mi)
    #pragma unroll
    for (int i = 0; i < 4; ++i){
      int slot = m0 + er0 + mi * 16 + i;
      if (slot >= count) continue;
      #pragma unroll
      for (int nj = 0; nj < 4; ++nj){
        int cc = n0 + ec0 + nj * 16;
        float v = fmaxf(acc[mi][nj][i] + b1e[cc], 0.0f);
        u16 hv, lv; bsplit(v, hv, lv);
        size_t o = (size_t)slot * FF + cc;
        hh[o] = hv; hl[o] = lv;
      }
    }
}

// MoE GEMM2 + combine: h x w2e^T -> out[token] += gval * (acc + b2)
__global__ __launch_bounds__(256) void k_moe2(const u16* __restrict__ hh, const u16* __restrict__ hl,
    const u16* __restrict__ w2Th, const u16* __restrict__ w2Tl, const float* __restrict__ b2e,
    const int* __restrict__ srcp, const int* __restrict__ cntp, int moff, int mcap,
    const float* __restrict__ gval, float* __restrict__ outp)
{
  int c = *cntp; if (c > CAPC) c = CAPC; c -= moff; if (c < 0) c = 0; if (c > mcap) c = mcap;
  const int count = c;
  int m0 = blockIdx.y * 128, n0 = blockIdx.x * 128;
  if (m0 >= count) return;
  const f4_t fz = {0.f,0.f,0.f,0.f};
  f4_t acc[4][4];
  #pragma unroll
  for (int i = 0; i < 4; ++i){ acc[i][0]=fz; acc[i][1]=fz; acc[i][2]=fz; acc[i][3]=fz; }
  gemm_core<128,false>(hh, hl, 4096, w2Th, w2Tl, 4096, m0, n0, 4096, nullptr, 0, acc);
  EPI_COORDS(128)
  #pragma unroll
  for (int mi = 0; mi < 4; ++mi)
    #pragma unroll
    for (int i = 0; i < 4; ++i){
      int slot = m0 + er0 + mi * 16 + i;
      if (slot >= count) continue;
      int t = srcp[slot];
      float g = gval[t];
      #pragma unroll
      for (int nj = 0; nj < 4; ++nj){
        int cc = n0 + ec0 + nj * 16;
        size_t o = (size_t)t * DD + cc;
        outp[o] += g * (acc[mi][nj][i] + b2e[cc]);
      }
    }
}

// ===================================================================
// host-side helpers
// ===================================================================
static void old_attention(const float* x, const float* amask,
    const float* wq, const float* bq, const float* wk, const float* bk,
    const float* wv, const float* bv, const float* wo, const float* bo,
    const float* g1, const float* be1, float* stats1, float* x1f, char* A,
    hipStream_t stream)
{
  float* qc  = (float*)(A + 0);
  float* kc  = (float*)(A + 2097152);
  float* vc  = (float*)(A + 4194304);
  float* sc  = (float*)(A + 6291456);
  float* o_h = (float*)(A + 14680064);
  ln_stats<<<NTOK, 256, 0, stream>>>(x, stats1);
  init_x1<<<8192, 256, 0, stream>>>(x, bo, x1f);
  for (int h = 0; h < 16; ++h){
    int nofs = h * 64;
    proj_gemm<<<dim3(1, 128), 256, 0, stream>>>(x, stats1, g1, be1, wq, bq, 0.125f, nofs, qc);
    proj_gemm<<<dim3(1, 128), 256, 0, stream>>>(x, stats1, g1, be1, wk, bk, 1.0f,   nofs, kc);
    proj_gemm<<<dim3(1, 128), 256, 0, stream>>>(x, stats1, g1, be1, wv, bv, 1.0f,   nofs, vc);
    for (int qt = 0; qt < 4; ++qt){
      int pl0 = qt * 2;
      score_gemm<<<dim3(16, 16, 2), 256, 0, stream>>>(qc, kc, sc, pl0);
      softmax_io<<<2048, 256, 0, stream>>>(sc, amask);
      pv_gemm<<<dim3(1, 16, 2), 256, 0, stream>>>(sc, vc, o_h, pl0);
    }
    oproj_acc<<<dim3(16, 128), 256, 0, stream>>>(o_h, wo, h, x1f);
  }
}

extern "C" void kernel_launch(void* const* d_in, const int* in_sizes, int n_in,
                              void* d_out, int out_size, void* d_ws, size_t ws_size,
                              hipStream_t stream)
{
  (void)in_sizes; (void)n_in;
  const float* x     = (const float*)d_in[0];
  const float* amask = (const float*)d_in[1];
  const float* wq = (const float*)d_in[2];  const float* bq = (const float*)d_in[3];
  const float* wk = (const float*)d_in[4];  const float* bk = (const float*)d_in[5];
  const float* wv = (const float*)d_in[6];  const float* bv = (const float*)d_in[7];
  const float* wo = (const float*)d_in[8];  const float* bo = (const float*)d_in[9];
  const float* g1 = (const float*)d_in[10]; const float* be1 = (const float*)d_in[11];
  const float* g2 = (const float*)d_in[12]; const float* be2 = (const float*)d_in[13];
  const float* gw = (const float*)d_in[14];
  const float* w1 = (const float*)d_in[15]; const float* b1 = (const float*)d_in[16];
  const float* w2 = (const float*)d_in[17]; const float* b2 = (const float*)d_in[18];
  float* out = (float*)d_out;
  char* W = (char*)d_ws;
  const size_t MB = 1048576ull;

  // ---------------- Tier A: full split-bf16 MFMA (needs 161 MB) ----------------
  if (ws_size >= 161 * MB){
    float* stats1 = (float*)(W + 0);
    float* stats2 = (float*)(W + 65536);
    float* logits = (float*)(W + 131072);
    float* gval   = (float*)(W + 393216);
    int*   src    = (int*)  (W + 425984);
    int*   cnt    = (int*)  (W + 557056);
    float* sums   = (float*)(W + 557312);

    u16* qh = (u16*)(W + 1*MB);   u16* ql = (u16*)(W + 17*MB);
    u16* kh = (u16*)(W + 33*MB);  u16* kl = (u16*)(W + 49*MB);
    u16* vh = (u16*)(W + 65*MB);  u16* vl = (u16*)(W + 81*MB);
    u16* xh = (u16*)(W + 97*MB);  u16* xl = (u16*)(W + 113*MB);
    u16* oh = (u16*)(W + 129*MB); u16* ol = (u16*)(W + 145*MB);
    // overlays (lifetimes verified):
    float* sc  = (float*)(W + 65*MB);            // after V transposed
    u16* ph  = (u16*)(W + 81*MB);  u16* pl_ = (u16*)(W + 89*MB);
    u16* vTh = (u16*)(W + 97*MB);  u16* vTl = (u16*)(W + 113*MB);   // after xh/xl dead
    u16* wTh = (u16*)(W + 129*MB); u16* wTl = (u16*)(W + 131*MB);   // before PV writes o
    u16* woTh= (u16*)(W + 97*MB);  u16* woTl= (u16*)(W + 99*MB);    // after vT dead
    u16* th  = qh; u16* tl = ql;                                     // after attention
    u16* w1Th= (u16*)(W + 33*MB);  u16* w1Tl= (u16*)(W + 41*MB);
    u16* w2Th= (u16*)(W + 49*MB);  u16* w2Tl= (u16*)(W + 57*MB);
    u16* hh  = (u16*)(W + 65*MB);  u16* hl  = (u16*)(W + 81*MB);

    hipMemsetAsync(cnt, 0, 512, stream);
    ln_stats<<<NTOK, 256, 0, stream>>>(x, stats1);
    k_ln_split<<<NTOK, 256, 0, stream>>>(x, stats1, g1, be1, xh, xl);

    k_split_T<<<dim3(16,16), 256, 0, stream>>>(wq, 1024, wTh, wTl, 1024);
    k_proj<<<dim3(8,64), 256, 0, stream>>>(xh, xl, wTh, wTl, bq, 0.125f, qh, ql);
    k_split_T<<<dim3(16,16), 256, 0, stream>>>(wk, 1024, wTh, wTl, 1024);
    k_proj<<<dim3(8,64), 256, 0, stream>>>(xh, xl, wTh, wTl, bk, 1.0f, kh, kl);
    k_split_T<<<dim3(16,16), 256, 0, stream>>>(wv, 1024, wTh, wTl, 1024);
    k_proj<<<dim3(8,64), 256, 0, stream>>>(xh, xl, wTh, wTl, bv, 1.0f, vh, vl);
    k_transpose_bf<<<dim3(16,2,128), 256, 0, stream>>>(vh, vl, vTh, vTl);

    for (int pc = 0; pc < 32; ++pc){
      int pl0 = pc * 4;
      k_scores<<<dim3(8,8,4), 256, 0, stream>>>(qh, ql, kh, kl, sc, pl0);
      k_softmax_split<<<4096, 256, 0, stream>>>(sc, amask, ph, pl_);
      k_pv<<<dim3(1,8,4), 256, 0, stream>>>(ph, pl_, vTh, vTl, oh, ol, pl0);
    }

    k_split_T<<<dim3(16,16), 256, 0, stream>>>(wo, 1024, woTh, woTl, 1024);
    k_oproj<<<dim3(8,64), 256, 0, stream>>>(oh, ol, woTh, woTl, x, bo, out);

    ln_stats<<<NTOK, 256, 0, stream>>>(out, stats2);
    logits_gemm<<<2048, 256, 0, stream>>>(out, stats2, g2, be2, gw, logits);
    routing_kernel<<<32, 256, 0, stream>>>(logits, gval, src, cnt, sums);
    laux_kernel<<<1, 64, 0, stream>>>(sums, cnt, out + (size_t)NTOK * DD);
    k_ln_split<<<NTOK, 256, 0, stream>>>(out, stats2, g2, be2, th, tl);

    for (int e = 0; e < 8; ++e){
      k_split_T<<<dim3(64,16), 256, 0, stream>>>(w1 + (size_t)e * DD * FF, 4096, w1Th, w1Tl, 1024);
      k_split_T<<<dim3(16,64), 256, 0, stream>>>(w2 + (size_t)e * FF * DD, 1024, w2Th, w2Tl, 4096);
      for (int c = 0; c < 2; ++c){
        int moff = c * 2048;
        k_moe1<<<dim3(32,16), 256, 0, stream>>>(th, tl, w1Th, w1Tl, b1 + (size_t)e * FF,
            src + e * CAPC + moff, cnt + e, moff, 2048, hh, hl);
        k_moe2<<<dim3(8,16), 256, 0, stream>>>(hh, hl, w2Th, w2Tl, b2 + (size_t)e * DD,
            src + e * CAPC + moff, cnt + e, moff, 2048, gval, out);
      }
    }
    return;
  }

  // ---------------- Tier B: old attention + MFMA MoE (needs 113 MB) ----------------
  if (ws_size >= 113 * MB){
    float* gval   = (float*)(W + 0);
    int*   src    = (int*)  (W + 32768);
    int*   cnt    = (int*)  (W + 163840);
    float* sums   = (float*)(W + 164096);
    float* stats1 = (float*)(W + 164352);
    float* stats2 = (float*)(W + 229888);
    float* logits = (float*)(W + 295424);
    float* x1f    = (float*)(W + 1048576);
    char*  A      = W + 1048576 + 33554432;

    u16* th  = (u16*)(W + 33*MB);  u16* tl  = (u16*)(W + 49*MB);
    u16* w1Th= (u16*)(W + 65*MB);  u16* w1Tl= (u16*)(W + 73*MB);
    u16* w2Th= (u16*)(W + 81*MB);  u16* w2Tl= (u16*)(W + 89*MB);
    u16* hh  = (u16*)(W + 97*MB);  u16* hl  = (u16*)(W + 105*MB);

    hipMemsetAsync(cnt, 0, 512, stream);
    old_attention(x, amask, wq, bq, wk, bk, wv, bv, wo, bo, g1, be1, stats1, x1f, A, stream);

    ln_stats<<<NTOK, 256, 0, stream>>>(x1f, stats2);
    logits_gemm<<<2048, 256, 0, stream>>>(x1f, stats2, g2, be2, gw, logits);
    routing_kernel<<<32, 256, 0, stream>>>(logits, gval, src, cnt, sums);
    laux_kernel<<<1, 64, 0, stream>>>(sums, cnt, out + (size_t)NTOK * DD);
    copy_x1<<<8192, 256, 0, stream>>>(x1f, out);
    k_ln_split<<<NTOK, 256, 0, stream>>>(x1f, stats2, g2, be2, th, tl);

    for (int e = 0; e < 8; ++e){
      k_split_T<<<dim3(64,16), 256, 0, stream>>>(w1 + (size_t)e * DD * FF, 4096, w1Th, w1Tl, 1024);
      k_split_T<<<dim3(16,64), 256, 0, stream>>>(w2 + (size_t)e * FF * DD, 1024, w2Th, w2Tl, 4096);
      for (int c = 0; c < 4; ++c){
        int moff = c * 1024;
        k_moe1<<<dim3(32,8), 256, 0, stream>>>(th, tl, w1Th, w1Tl, b1 + (size_t)e * FF,
            src + e * CAPC + moff, cnt + e, moff, 1024, hh, hl);
        k_moe2<<<dim3(8,8), 256, 0, stream>>>(hh, hl, w2Th, w2Tl, b2 + (size_t)e * DD,
            src + e * CAPC + moff, cnt + e, moff, 1024, gval, out);
      }
    }
    return;
  }

  // ---------------- Tier C: previous fp32 kernel ----------------
  const size_t NEED = 51380224;
  if (ws_size < NEED){
    zerofill_kernel<<<(out_size + 255) / 256, 256, 0, stream>>>(out, out_size);
    return;
  }
  float* gval   = (float*)(W + 0);
  int*   src    = (int*)  (W + 32768);
  int*   cnt    = (int*)  (W + 163840);
  float* sums   = (float*)(W + 164096);
  float* stats1 = (float*)(W + 164352);
  float* stats2 = (float*)(W + 229888);
  float* logits = (float*)(W + 295424);
  float* x1f    = (float*)(W + 1048576);
  char* A = W + 1048576 + 33554432;
  float* hbuf = (float*)(A + 0);

  hipMemsetAsync(cnt, 0, 512, stream);
  old_attention(x, amask, wq, bq, wk, bk, wv, bv, wo, bo, g1, be1, stats1, x1f, A, stream);

  ln_stats<<<NTOK, 256, 0, stream>>>(x1f, stats2);
  logits_gemm<<<2048, 256, 0, stream>>>(x1f, stats2, g2, be2, gw, logits);
  routing_kernel<<<32, 256, 0, stream>>>(logits, gval, src, cnt, sums);
  laux_kernel<<<1, 64, 0, stream>>>(sums, cnt, out + (size_t)NTOK * DD);
  copy_x1<<<8192, 256, 0, stream>>>(x1f, out);

  for (int e = 0; e < 8; ++e){
    for (int ccn = 0; ccn < 4; ++ccn){
      int moff = ccn * 1024;
      moe1_gemm<<<dim3(64, 16), 256, 0, stream>>>(x1f, stats2, g2, be2,
          src + e * CAPC + moff, cnt + e, moff, w1 + (size_t)e * (DD * FF), b1 + (size_t)e * FF, hbuf);
      moe2_gemm<<<dim3(16, 16), 256, 0, stream>>>(hbuf, w2 + (size_t)e * (FF * DD),
          b2 + (size_t)e * DD, src + e * CAPC + moff, cnt + e, moff, gval, out);
    }
  }
}

// Round 2
// 2097.078 us; speedup vs baseline: 7.9826x; 1.9220x over previous
//
#include <hip/hip_runtime.h>

#define DD   1024
#define FF   4096
#define NTOK 8192
#define CAPC 4096

// ===================================================================
// Tier A (ws >= 161 MB, proven): split-bf16 MFMA pipeline.
//   - attention path: 3-term Markidis split (fp32-class; argmax-critical)
//   - MoE path: bf16 weights/h (TERMS=2/1), experts merged per group of 4
// Tier C fallback: old fp32 kernel.
// ===================================================================

typedef unsigned short u16;
typedef __attribute__((ext_vector_type(8))) short bfrag;   // 8 bf16 = 4 VGPR
typedef __attribute__((ext_vector_type(4))) float f4_t;

#define MFMA(a,b,c) __builtin_amdgcn_mfma_f32_16x16x32_bf16(a,b,c,0,0,0)

__device__ __forceinline__ u16 f2bf(float f){
  unsigned u = __float_as_uint(f);
  u += 0x7FFFu + ((u >> 16) & 1u);          // RNE
  return (u16)(u >> 16);
}
__device__ __forceinline__ float bf2f(u16 h){
  return __uint_as_float(((unsigned)h) << 16);
}
__device__ __forceinline__ void bsplit(float v, u16& h, u16& l){
  h = f2bf(v);
  l = f2bf(v - bf2f(h));
}

__device__ __forceinline__ float block_sum(float v, float* sh){
  #pragma unroll
  for (int off = 32; off > 0; off >>= 1) v += __shfl_down(v, off, 64);
  if ((threadIdx.x & 63) == 0) sh[threadIdx.x >> 6] = v;
  __syncthreads();
  float r = (sh[0] + sh[1]) + (sh[2] + sh[3]);
  __syncthreads();
  return r;
}
__device__ __forceinline__ float block_max(float v, float* sh){
  #pragma unroll
  for (int off = 32; off > 0; off >>= 1) v = fmaxf(v, __shfl_down(v, off, 64));
  if ((threadIdx.x & 63) == 0) sh[threadIdx.x >> 6] = v;
  __syncthreads();
  float r = fmaxf(fmaxf(sh[0], sh[1]), fmaxf(sh[2], sh[3]));
  __syncthreads();
  return r;
}

// ============== old fp32 tile-GEMM core (Tier C fallback) ==============
#define GEMM_CORE(KTILES, LOADA, LOADB) \
  __shared__ float As[64][17]; \
  __shared__ float Bs[16][65]; \
  float cc_[4][4] = {{0,0,0,0},{0,0,0,0},{0,0,0,0},{0,0,0,0}}; \
  const int tx = threadIdx.x & 15, ty = threadIdx.x >> 4; \
  for (int kt = 0; kt < (KTILES); ++kt){ \
    _Pragma("unroll") \
    for (int q_ = 0; q_ < 4; ++q_){ \
      int id_ = q_ * 256 + threadIdx.x; \
      { int r_ = id_ >> 4; int k_ = kt * 16 + (id_ & 15); As[r_][id_ & 15] = (LOADA); } \
      { int c_ = id_ & 63; int k_ = kt * 16 + (id_ >> 6); Bs[id_ >> 6][c_] = (LOADB); } \
    } \
    __syncthreads(); \
    _Pragma("unroll") \
    for (int kk_ = 0; kk_ < 16; ++kk_){ \
      float a_[4], b_[4]; \
      _Pragma("unroll") \
      for (int i_ = 0; i_ < 4; ++i_) a_[i_] = As[ty * 4 + i_][kk_]; \
      _Pragma("unroll") \
      for (int j_ = 0; j_ < 4; ++j_) b_[j_] = Bs[kk_][tx * 4 + j_]; \
      _Pragma("unroll") \
      for (int i_ = 0; i_ < 4; ++i_) \
        _Pragma("unroll") \
        for (int j_ = 0; j_ < 4; ++j_) cc_[i_][j_] += a_[i_] * b_[j_]; \
    } \
    __syncthreads(); \
  }

__device__ __forceinline__ float ln_elem(const float* __restrict__ x, const float* __restrict__ st,
    const float* __restrict__ g, const float* __restrict__ be, int t, int k){
  return (x[(size_t)t * DD + k] - st[2 * t]) * st[2 * t + 1] * g[k] + be[k];
}

__global__ __launch_bounds__(256) void ln_stats(const float* __restrict__ xb, float* __restrict__ stats)
{
  __shared__ float sh[4];
  int n = blockIdx.x, tid = threadIdx.x;
  float4 xv = *(const float4*)(xb + (size_t)n * DD + tid * 4);
  float v[4] = { xv.x, xv.y, xv.z, xv.w };
  float s = (v[0] + v[1]) + (v[2] + v[3]);
  s = block_sum(s, sh);
  float m = s * (1.0f / DD);
  float q = 0;
  #pragma unroll
  for (int i = 0; i < 4; ++i){ float d = v[i] - m; q += d * d; }
  q = block_sum(q, sh);
  if (tid == 0){
    stats[2 * n]     = m;
    stats[2 * n + 1] = 1.0f / sqrtf(q * (1.0f / DD) + 1e-5f);
  }
}

__global__ __launch_bounds__(256) void init_x1(const float* __restrict__ x,
    const float* __restrict__ bo, float* __restrict__ x1f)
{
  size_t i = (size_t)blockIdx.x * 1024 + threadIdx.x * 4;
  float4 xv = *(const float4*)(x + i);
  float4 bv = *(const float4*)(bo + (i & (DD - 1)));
  xv.x += bv.x; xv.y += bv.y; xv.z += bv.z; xv.w += bv.w;
  *(float4*)(x1f + i) = xv;
}

__global__ __launch_bounds__(256) void proj_gemm(const float* __restrict__ xin,
    const float* __restrict__ st, const float* __restrict__ g, const float* __restrict__ be,
    const float* __restrict__ w, const float* __restrict__ bias, float escale, int nofs,
    float* __restrict__ outq)
{
  const int n0 = blockIdx.x * 64, m0 = blockIdx.y * 64;
  GEMM_CORE(64,
    (ln_elem(xin, st, g, be, m0 + r_, k_)),
    (w[(size_t)k_ * DD + nofs + n0 + c_]))
  #pragma unroll
  for (int i = 0; i < 4; ++i){
    int t = m0 + ty * 4 + i, s = t >> 3, b = t & 7;
    #pragma unroll
    for (int j = 0; j < 4; ++j){
      int col = n0 + tx * 4 + j;
      outq[(size_t)b * 65536 + (size_t)s * 64 + col] = (cc_[i][j] + bias[nofs + col]) * escale;
    }
  }
}

__global__ __launch_bounds__(256) void score_gemm(const float* __restrict__ qc,
    const float* __restrict__ kc, float* __restrict__ sc, int pl0)
{
  const int n0 = blockIdx.x * 64, m0 = blockIdx.y * 64, pz = blockIdx.z;
  const size_t pb = (size_t)(pl0 + pz) * 65536;
  GEMM_CORE(4,
    (qc[pb + (size_t)(m0 + r_) * 64 + k_]),
    (kc[pb + (size_t)(n0 + c_) * 64 + k_]))
  #pragma unroll
  for (int i = 0; i < 4; ++i){
    int row = m0 + ty * 4 + i;
    #pragma unroll
    for (int j = 0; j < 4; ++j)
      sc[(size_t)pz * 1048576 + (size_t)row * 1024 + n0 + tx * 4 + j] = cc_[i][j];
  }
}

__global__ __launch_bounds__(256) void softmax_io(float* __restrict__ sc, const float* __restrict__ mask)
{
  __shared__ float sh[4];
  int row = blockIdx.x, tid = threadIdx.x;
  int q = row & 1023;
  float* srow = sc + (size_t)row * 1024;
  const float* mrow = mask + (size_t)q * 1024;
  int j0 = tid * 4;
  float4 sv = *(const float4*)(srow + j0);
  float4 mv = *(const float4*)(mrow + j0);
  float v[4] = { sv.x + mv.x, sv.y + mv.y, sv.z + mv.z, sv.w + mv.w };
  float mx = fmaxf(fmaxf(v[0], v[1]), fmaxf(v[2], v[3]));
  mx = block_max(mx, sh);
  float e[4]; float l = 0;
  #pragma unroll
  for (int i = 0; i < 4; ++i){ e[i] = expf(v[i] - mx); l += e[i]; }
  l = block_sum(l, sh);
  float inv = 1.0f / l;
  #pragma unroll
  for (int i = 0; i < 4; ++i) srow[j0 + i] = e[i] * inv;
}

__global__ __launch_bounds__(256) void pv_gemm(const float* __restrict__ sc,
    const float* __restrict__ vc, float* __restrict__ o_h, int pl0)
{
  const int n0 = blockIdx.x * 64, m0 = blockIdx.y * 64, pz = blockIdx.z;
  const size_t pb = (size_t)(pl0 + pz) * 65536;
  GEMM_CORE(64,
    (sc[(size_t)pz * 1048576 + (size_t)(m0 + r_) * 1024 + k_]),
    (vc[pb + (size_t)k_ * 64 + n0 + c_]))
  int b = pl0 + pz;
  #pragma unroll
  for (int i = 0; i < 4; ++i){
    int s = m0 + ty * 4 + i;
    #pragma unroll
    for (int j = 0; j < 4; ++j)
      o_h[(size_t)b * 65536 + (size_t)s * 64 + n0 + tx * 4 + j] = cc_[i][j];
  }
}

__global__ __launch_bounds__(256) void oproj_acc(const float* __restrict__ o_h,
    const float* __restrict__ wo, int h, float* __restrict__ x1f)
{
  const int n0 = blockIdx.x * 64, m0 = blockIdx.y * 64;
  GEMM_CORE(4,
    (o_h[(size_t)((m0 + r_) & 7) * 65536 + (size_t)((m0 + r_) >> 3) * 64 + k_]),
    (wo[(size_t)(h * 64 + k_) * DD + n0 + c_]))
  #pragma unroll
  for (int i = 0; i < 4; ++i){
    size_t row = m0 + ty * 4 + i;
    #pragma unroll
    for (int j = 0; j < 4; ++j){
      size_t o = row * DD + n0 + tx * 4 + j;
      x1f[o] += cc_[i][j];
    }
  }
}

__global__ __launch_bounds__(256) void logits_gemm(const float* __restrict__ x1f,
    const float* __restrict__ st2, const float* __restrict__ g2, const float* __restrict__ be2,
    const float* __restrict__ gw, float* __restrict__ logits)
{
  int n = blockIdx.x * 4 + (threadIdx.x >> 6);
  int l = threadIdx.x & 63;
  float m = st2[2 * n], rs = st2[2 * n + 1];
  float acc[8] = {0,0,0,0,0,0,0,0};
  for (int i = 0; i < 16; ++i){
    int d = i * 64 + l;
    float t = (x1f[(size_t)n * DD + d] - m) * rs * g2[d] + be2[d];
    const float* gr = gw + (size_t)d * 8;
    #pragma unroll
    for (int e = 0; e < 8; ++e) acc[e] += t * gr[e];
  }
  #pragma unroll
  for (int e = 0; e < 8; ++e){
    #pragma unroll
    for (int off = 32; off > 0; off >>= 1) acc[e] += __shfl_down(acc[e], off, 64);
  }
  if (l == 0){
    #pragma unroll
    for (int e = 0; e < 8; ++e) logits[(size_t)n * 8 + e] = acc[e];
  }
}

__global__ void routing_kernel(const float* __restrict__ logits, float* __restrict__ gval,
    int* __restrict__ src, int* __restrict__ cnt, float* __restrict__ sums)
{
  int n = blockIdx.x * 256 + threadIdx.x;
  if (n >= NTOK) return;
  const float* L = logits + (size_t)n * 8;
  float l[8];
  #pragma unroll
  for (int e = 0; e < 8; ++e) l[e] = L[e];
  float best = l[0]; int be = 0;
  #pragma unroll
  for (int e = 1; e < 8; ++e) if (l[e] > best){ best = l[e]; be = e; }
  float g[8], es = 0;
  #pragma unroll
  for (int e = 0; e < 8; ++e){ g[e] = expf(l[e] - best); es += g[e]; }
  #pragma unroll
  for (int e = 0; e < 8; ++e) atomicAdd(&sums[e], g[e] / es);
  float gv = g[be] / es;
  int r = atomicAdd(&cnt[be], 1);
  bool keep = r < CAPC;
  gval[n] = keep ? gv : 0.0f;
  if (keep) src[be * CAPC + r] = n;
}

__global__ void laux_kernel(const float* __restrict__ sums, const int* __restrict__ cnt,
    float* __restrict__ outp)
{
  if (threadIdx.x == 0 && blockIdx.x == 0){
    float la = 0;
    for (int e = 0; e < 8; ++e) la += (sums[e] * (1.0f / NTOK)) * ((float)cnt[e] * (1.0f / NTOK));
    outp[0] = la * 8.0f;
  }
}

__global__ __launch_bounds__(256) void copy_x1(const float* __restrict__ x1f, float* __restrict__ outp)
{
  size_t i = (size_t)blockIdx.x * 1024 + threadIdx.x * 4;
  *(float4*)(outp + i) = *(const float4*)(x1f + i);
}

__global__ __launch_bounds__(256) void moe1_gemm(const float* __restrict__ x1f,
    const float* __restrict__ st2, const float* __restrict__ g2, const float* __restrict__ be2,
    const int* __restrict__ srcp, const int* __restrict__ cntp, int moff,
    const float* __restrict__ w1e, const float* __restrict__ b1e, float* __restrict__ hbuf)
{
  int c = *cntp; if (c > CAPC) c = CAPC; c -= moff; if (c < 0) c = 0;
  const int count = c < 1024 ? c : 1024;
  const int n0 = blockIdx.x * 64, m0 = blockIdx.y * 64;
  if (m0 >= count) return;
  GEMM_CORE(64,
    (ln_elem(x1f, st2, g2, be2, ((m0 + r_) < count ? srcp[m0 + r_] : 0), k_)),
    (w1e[(size_t)k_ * FF + n0 + c_]))
  #pragma unroll
  for (int i = 0; i < 4; ++i){
    int slot = m0 + ty * 4 + i;
    if (slot >= count) continue;
    #pragma unroll
    for (int j = 0; j < 4; ++j){
      int col = n0 + tx * 4 + j;
      hbuf[(size_t)slot * FF + col] = fmaxf(cc_[i][j] + b1e[col], 0.0f);
    }
  }
}

__global__ __launch_bounds__(256) void moe2_gemm(const float* __restrict__ hbuf,
    const float* __restrict__ w2e, const float* __restrict__ b2e, const int* __restrict__ srcp,
    const int* __restrict__ cntp, int moff, const float* __restrict__ gval,
    float* __restrict__ outp)
{
  int c = *cntp; if (c > CAPC) c = CAPC; c -= moff; if (c < 0) c = 0;
  const int count = c < 1024 ? c : 1024;
  const int n0 = blockIdx.x * 64, m0 = blockIdx.y * 64;
  if (m0 >= count) return;
  GEMM_CORE(256,
    (hbuf[(size_t)(m0 + r_) * FF + k_]),
    (w2e[(size_t)k_ * DD + n0 + c_]))
  #pragma unroll
  for (int i = 0; i < 4; ++i){
    int slot = m0 + ty * 4 + i;
    if (slot >= count) continue;
    int t = srcp[slot];
    float gv = gval[t];
    #pragma unroll
    for (int j = 0; j < 4; ++j){
      int col = n0 + tx * 4 + j;
      size_t o = (size_t)t * DD + col;
      outp[o] += gv * (cc_[i][j] + b2e[col]);
    }
  }
}

__global__ void zerofill_kernel(float* o, int nelem){
  int i = blockIdx.x * 256 + threadIdx.x;
  if (i < nelem) o[i] = 0.0f;
}

// ===================================================================
// unified split-bf16 MFMA GEMM core.  C = A * B^T.
// AMODE: 0 = direct rows, 1 = gather rows via srcp (clamped), 2 = clamp rows to count.
// TERMS: 3 = Ah*Bh+Ah*Bl+Al*Bh ; 2 = Ah*Bh+Al*Bh (B single plane) ; 1 = Ah*Bh.
// LDS rows padded to 40 u16 (80 B) -> fragment reads <=2-way bank aliasing.
// ===================================================================
template<int BN, int AMODE, int TERMS>
__device__ __forceinline__ void gemm_core(
    const u16* __restrict__ Ah, const u16* __restrict__ Al, int lda,
    const u16* __restrict__ Bh, const u16* __restrict__ Bl, int ldb,
    int m0, int n0, int K, const int* __restrict__ srcp, int count,
    f4_t (&acc)[4][BN / 32])
{
  constexpr int NJ  = BN / 32;
  constexpr int LDP = 40;
  __shared__ u16 AsH[128 * LDP];
  __shared__ u16 AsL[(TERMS >= 2) ? 128 * LDP : LDP];
  __shared__ u16 BsH[BN * LDP];
  __shared__ u16 BsL[(TERMS >= 3) ? BN * LDP : LDP];
  const int tid = threadIdx.x;

  const int ar = tid >> 1;
  long arow;
  if constexpr (AMODE == 1){
    int r = m0 + ar; if (r >= count) r = (count > 0) ? count - 1 : 0;
    arow = srcp[r];
  } else if constexpr (AMODE == 2){
    int r = m0 + ar; if (r >= count) r = count - 1;
    arow = r;
  } else {
    arow = m0 + ar;
  }
  const size_t abase = (size_t)arow * lda + (size_t)((tid & 1) * 16);

  int br, boff;
  if constexpr (BN == 128){ br = tid >> 1; boff = (tid & 1) * 16; }
  else                    { br = tid >> 2; boff = (tid & 3) * 8; }
  const size_t bbase = (size_t)(n0 + br) * ldb + boff;

  u16* awh = &AsH[ar * LDP + (tid & 1) * 16];
  u16* awl = &AsL[(TERMS >= 2) ? (ar * LDP + (tid & 1) * 16) : 0];
  u16* bwh = &BsH[br * LDP + boff];
  u16* bwl = &BsL[(TERMS >= 3) ? (br * LDP + boff) : 0];

  uint4 rah0, rah1, ral0{}, ral1{}, rbh0, rbh1{}, rbl0{}, rbl1{};
  rah0 = *(const uint4*)(Ah + abase);  rah1 = *(const uint4*)(Ah + abase + 8);
  if constexpr (TERMS >= 2){ ral0 = *(const uint4*)(Al + abase); ral1 = *(const uint4*)(Al + abase + 8); }
  if constexpr (BN == 128){
    rbh0 = *(const uint4*)(Bh + bbase);  rbh1 = *(const uint4*)(Bh + bbase + 8);
    if constexpr (TERMS >= 3){ rbl0 = *(const uint4*)(Bl + bbase); rbl1 = *(const uint4*)(Bl + bbase + 8); }
  } else {
    rbh0 = *(const uint4*)(Bh + bbase);
    if constexpr (TERMS >= 3){ rbl0 = *(const uint4*)(Bl + bbase); }
  }

  const int KT = K >> 5;
  const int lane = tid & 63, wv = tid >> 6;
  const int wr = wv >> 1, wc = wv & 1;
  const int fr = lane & 15, fk = (lane >> 4) * 8;

  for (int kt = 0; kt < KT; ++kt){
    __syncthreads();
    *(uint4*)(awh) = rah0; *(uint4*)(awh + 8) = rah1;
    if constexpr (TERMS >= 2){ *(uint4*)(awl) = ral0; *(uint4*)(awl + 8) = ral1; }
    if constexpr (BN == 128){
      *(uint4*)(bwh) = rbh0; *(uint4*)(bwh + 8) = rbh1;
      if constexpr (TERMS >= 3){ *(uint4*)(bwl) = rbl0; *(uint4*)(bwl + 8) = rbl1; }
    } else {
      *(uint4*)(bwh) = rbh0;
      if constexpr (TERMS >= 3){ *(uint4*)(bwl) = rbl0; }
    }
    __syncthreads();
    if (kt + 1 < KT){
      const size_t a = abase + (size_t)(kt + 1) * 32;
      const size_t b = bbase + (size_t)(kt + 1) * 32;
      rah0 = *(const uint4*)(Ah + a); rah1 = *(const uint4*)(Ah + a + 8);
      if constexpr (TERMS >= 2){ ral0 = *(const uint4*)(Al + a); ral1 = *(const uint4*)(Al + a + 8); }
      if constexpr (BN == 128){
        rbh0 = *(const uint4*)(Bh + b); rbh1 = *(const uint4*)(Bh + b + 8);
        if constexpr (TERMS >= 3){ rbl0 = *(const uint4*)(Bl + b); rbl1 = *(const uint4*)(Bl + b + 8); }
      } else {
        rbh0 = *(const uint4*)(Bh + b);
        if constexpr (TERMS >= 3){ rbl0 = *(const uint4*)(Bl + b); }
      }
    }
    bfrag a_h[4], a_l[4];
    #pragma unroll
    for (int mi = 0; mi < 4; ++mi){
      int r = wr * 64 + mi * 16 + fr;
      a_h[mi] = *(const bfrag*)&AsH[r * LDP + fk];
      if constexpr (TERMS >= 2) a_l[mi] = *(const bfrag*)&AsL[r * LDP + fk];
    }
    #pragma unroll
    for (int nj = 0; nj < NJ; ++nj){
      int cidx = wc * (BN / 2) + nj * 16 + fr;
      bfrag b_h = *(const bfrag*)&BsH[cidx * LDP + fk];
      bfrag b_l;
      if constexpr (TERMS >= 3) b_l = *(const bfrag*)&BsL[cidx * LDP + fk];
      #pragma unroll
      for (int mi = 0; mi < 4; ++mi){
        acc[mi][nj] = MFMA(a_h[mi], b_h, acc[mi][nj]);
        if constexpr (TERMS >= 3) acc[mi][nj] = MFMA(a_h[mi], b_l, acc[mi][nj]);
        if constexpr (TERMS >= 2) acc[mi][nj] = MFMA(a_l[mi], b_h, acc[mi][nj]);
      }
    }
  }
}

#define EPI_COORDS(BNv) \
  const int lane_ = threadIdx.x & 63, wid_ = threadIdx.x >> 6; \
  const int er0 = (wid_ >> 1) * 64 + ((lane_ >> 4) << 2); \
  const int ec0 = (wid_ & 1) * ((BNv) / 2) + (lane_ & 15);

#define ACC_INIT4 \
  const f4_t fz_ = {0.f,0.f,0.f,0.f}; \
  f4_t acc[4][4]; \
  _Pragma("unroll") \
  for (int i_ = 0; i_ < 4; ++i_){ acc[i_][0]=fz_; acc[i_][1]=fz_; acc[i_][2]=fz_; acc[i_][3]=fz_; }

// ---------- conversion helpers ----------

// LN + split of fp32 [8192][1024] -> bf16 hi/lo planes
__global__ __launch_bounds__(256) void k_ln_split(const float* __restrict__ xb,
    const float* __restrict__ st, const float* __restrict__ g, const float* __restrict__ be,
    u16* __restrict__ oh, u16* __restrict__ ol)
{
  int n = blockIdx.x, j = threadIdx.x * 4;
  float m = st[2 * n], rs = st[2 * n + 1];
  float4 xv = *(const float4*)(xb + (size_t)n * DD + j);
  float4 gv = *(const float4*)(g + j);
  float4 bv = *(const float4*)(be + j);
  float t0 = (xv.x - m) * rs * gv.x + bv.x;
  float t1 = (xv.y - m) * rs * gv.y + bv.y;
  float t2 = (xv.z - m) * rs * gv.z + bv.z;
  float t3 = (xv.w - m) * rs * gv.w + bv.w;
  ushort4 hv, lv;
  bsplit(t0, hv.x, lv.x); bsplit(t1, hv.y, lv.y);
  bsplit(t2, hv.z, lv.z); bsplit(t3, hv.w, lv.w);
  *(ushort4*)(oh + (size_t)n * DD + j) = hv;
  *(ushort4*)(ol + (size_t)n * DD + j) = lv;
}

// fp32 W[K][ld] -> transposed split planes [N][ldo]
__global__ __launch_bounds__(256) void k_split_T(const float* __restrict__ w, int ld,
    u16* __restrict__ th, u16* __restrict__ tl, int ldo)
{
  __shared__ float T[64][65];
  int n0 = blockIdx.x * 64, k0 = blockIdx.y * 64;
  int tx = threadIdx.x & 63, ty = threadIdx.x >> 6;
  #pragma unroll
  for (int r = 0; r < 16; ++r)
    T[ty * 16 + r][tx] = w[(size_t)(k0 + ty * 16 + r) * ld + n0 + tx];
  __syncthreads();
  #pragma unroll
  for (int r = 0; r < 16; ++r){
    int n = ty * 16 + r;
    float v = T[tx][n];
    u16 h, l; bsplit(v, h, l);
    size_t o = (size_t)(n0 + n) * ldo + k0 + tx;
    th[o] = h; tl[o] = l;
  }
}

// fp32 W[K][ld] -> transposed SINGLE bf16 plane [N][ldo], per-expert (z)
__global__ __launch_bounds__(256) void k_split_T1(const float* __restrict__ w, int ld,
    u16* __restrict__ th, int ldo, size_t wstride, size_t ostride)
{
  __shared__ float T[64][65];
  const float* we = w + (size_t)blockIdx.z * wstride;
  u16* te = th + (size_t)blockIdx.z * ostride;
  int n0 = blockIdx.x * 64, k0 = blockIdx.y * 64;
  int tx = threadIdx.x & 63, ty = threadIdx.x >> 6;
  #pragma unroll
  for (int r = 0; r < 16; ++r)
    T[ty * 16 + r][tx] = we[(size_t)(k0 + ty * 16 + r) * ld + n0 + tx];
  __syncthreads();
  #pragma unroll
  for (int r = 0; r < 16; ++r){
    int n = ty * 16 + r;
    te[(size_t)(n0 + n) * ldo + k0 + tx] = f2bf(T[tx][n]);
  }
}

// bf16 planes [pair][1024][64] -> [pair][64][1024]  (V -> V^T)
__global__ __launch_bounds__(256) void k_transpose_bf(const u16* __restrict__ vh,
    const u16* __restrict__ vl, u16* __restrict__ vTh, u16* __restrict__ vTl)
{
  __shared__ u16 T[64][65];
  const u16* src = blockIdx.y ? vl : vh;
  u16* dst = blockIdx.y ? vTl : vTh;
  int pair = blockIdx.z, s0 = blockIdx.x * 64;
  src += (size_t)pair * 65536; dst += (size_t)pair * 65536;
  int tx = threadIdx.x & 63, ty = threadIdx.x >> 6;
  #pragma unroll
  for (int r = 0; r < 16; ++r)
    T[ty * 16 + r][tx] = src[(size_t)(s0 + ty * 16 + r) * 64 + tx];
  __syncthreads();
  #pragma unroll
  for (int r = 0; r < 16; ++r){
    int hd = ty * 16 + r;
    dst[(size_t)hd * 1024 + s0 + tx] = T[tx][hd];
  }
}

// in-place softmax over fp32 score rows (mask pre-added); writes split bf16 P
// planes INTO the same buffer viewed as u16[row][2048]: hi at +0, lo at +1024.
// One wave per row; no cross-wave sync needed.
__global__ __launch_bounds__(256) void k_softmax_ip(float* __restrict__ sc)
{
  int row = blockIdx.x * 4 + (threadIdx.x >> 6);
  int lane = threadIdx.x & 63;
  float* srow = sc + (size_t)row * 1024;
  float4 a[4];
  #pragma unroll
  for (int j = 0; j < 4; ++j) a[j] = *(const float4*)(srow + j * 256 + lane * 4);
  float mx = -1e30f;
  #pragma unroll
  for (int j = 0; j < 4; ++j)
    mx = fmaxf(mx, fmaxf(fmaxf(a[j].x, a[j].y), fmaxf(a[j].z, a[j].w)));
  #pragma unroll
  for (int off = 32; off > 0; off >>= 1) mx = fmaxf(mx, __shfl_xor(mx, off, 64));
  float e[16]; float s = 0;
  #pragma unroll
  for (int j = 0; j < 4; ++j){
    e[j*4+0] = expf(a[j].x - mx); e[j*4+1] = expf(a[j].y - mx);
    e[j*4+2] = expf(a[j].z - mx); e[j*4+3] = expf(a[j].w - mx);
    s += (e[j*4+0] + e[j*4+1]) + (e[j*4+2] + e[j*4+3]);
  }
  #pragma unroll
  for (int off = 32; off > 0; off >>= 1) s += __shfl_xor(s, off, 64);
  float inv = 1.0f / s;
  u16* prow = (u16*)srow;
  #pragma unroll
  for (int j = 0; j < 4; ++j){
    ushort4 hv, lv;
    bsplit(e[j*4+0] * inv, hv.x, lv.x); bsplit(e[j*4+1] * inv, hv.y, lv.y);
    bsplit(e[j*4+2] * inv, hv.z, lv.z); bsplit(e[j*4+3] * inv, hv.w, lv.w);
    int k = j * 256 + lane * 4;
    *(ushort4*)(prow + k) = hv;
    *(ushort4*)(prow + 1024 + k) = lv;
  }
}

// ---------- MFMA GEMM wrappers ----------

// merged QKV projection: [8192][1024] x wqkv^T[3072][1024] -> per-(b,h) planes
__global__ __launch_bounds__(256) void k_proj_qkv(const u16* __restrict__ xh, const u16* __restrict__ xl,
    const u16* __restrict__ wTh, const u16* __restrict__ wTl,
    const float* __restrict__ bq, const float* __restrict__ bk, const float* __restrict__ bv,
    u16* __restrict__ qh, u16* __restrict__ ql, u16* __restrict__ kh, u16* __restrict__ kl,
    u16* __restrict__ vh, u16* __restrict__ vl)
{
  ACC_INIT4
  int m0 = blockIdx.y * 128, n0 = blockIdx.x * 128;
  gemm_core<128,0,3>(xh, xl, 1024, wTh, wTl, 1024, m0, n0, 1024, nullptr, 0, acc);
  const int sel = n0 >> 10;
  const float* bias = sel == 0 ? bq : (sel == 1 ? bk : bv);
  const float scale = sel == 0 ? 0.125f : 1.0f;
  u16* doh = sel == 0 ? qh : (sel == 1 ? kh : vh);
  u16* dol = sel == 0 ? ql : (sel == 1 ? kl : vl);
  const int nb = n0 & 1023;
  EPI_COORDS(128)
  #pragma unroll
  for (int mi = 0; mi < 4; ++mi){
    #pragma unroll
    for (int i = 0; i < 4; ++i){
      int t = m0 + er0 + mi * 16 + i;
      int s = t >> 3, b = t & 7;
      #pragma unroll
      for (int nj = 0; nj < 4; ++nj){
        int cc = nb + ec0 + nj * 16;
        float v = (acc[mi][nj][i] + bias[cc]) * scale;
        u16 hv, lv; bsplit(v, hv, lv);
        size_t o = (size_t)(b * 16 + (cc >> 6)) * 65536 + (size_t)s * 64 + (cc & 63);
        doh[o] = hv; dol[o] = lv;
      }
    }
  }
}

// scores + mask: per pair, Q[1024][64] x K^T -> fp32 sc chunk [8][1024][1024]
__global__ __launch_bounds__(256) void k_scores(const u16* __restrict__ qh, const u16* __restrict__ ql,
    const u16* __restrict__ kh, const u16* __restrict__ kl, const float* __restrict__ mask,
    float* __restrict__ sc, int pl0)
{
  ACC_INIT4
  int zi = blockIdx.z;
  size_t pb = (size_t)(pl0 + zi) * 65536;
  int m0 = blockIdx.y * 128, n0 = blockIdx.x * 128;
  gemm_core<128,0,3>(qh + pb, ql + pb, 64, kh + pb, kl + pb, 64, m0, n0, 64, nullptr, 0, acc);
  float* scp = sc + ((size_t)zi << 20);
  EPI_COORDS(128)
  #pragma unroll
  for (int mi = 0; mi < 4; ++mi)
    #pragma unroll
    for (int i = 0; i < 4; ++i){
      int row = m0 + er0 + mi * 16 + i;
      #pragma unroll
      for (int nj = 0; nj < 4; ++nj){
        int col = n0 + ec0 + nj * 16;
        scp[(size_t)row * 1024 + col] = acc[mi][nj][i] + mask[(size_t)row * 1024 + col];
      }
    }
}

// PV: P (in-place planes, lda=2048: hi at +0, lo at +1024) x V^T[64][1024]
__global__ __launch_bounds__(256) void k_pv(const u16* __restrict__ pbuf,
    const u16* __restrict__ vTh, const u16* __restrict__ vTl,
    u16* __restrict__ oh, u16* __restrict__ ol, int pl0)
{
  const f4_t fz = {0.f,0.f,0.f,0.f};
  f4_t acc[4][2];
  #pragma unroll
  for (int i = 0; i < 4; ++i){ acc[i][0]=fz; acc[i][1]=fz; }
  int zi = blockIdx.z;
  int pair = pl0 + zi;
  int m0 = blockIdx.y * 128;
  const u16* pa = pbuf + ((size_t)zi << 21);
  gemm_core<64,0,3>(pa, pa + 1024, 2048,
                    vTh + (size_t)pair * 65536, vTl + (size_t)pair * 65536, 1024,
                    m0, 0, 1024, nullptr, 0, acc);
  int b = pair >> 4, hh = pair & 15;
  EPI_COORDS(64)
  #pragma unroll
  for (int mi = 0; mi < 4; ++mi)
    #pragma unroll
    for (int i = 0; i < 4; ++i){
      int s = m0 + er0 + mi * 16 + i;
      size_t t = (size_t)(s * 8 + b);
      #pragma unroll
      for (int nj = 0; nj < 2; ++nj){
        int cl = ec0 + nj * 16;
        u16 hv, lv; bsplit(acc[mi][nj][i], hv, lv);
        size_t o = t * 1024 + hh * 64 + cl;
        oh[o] = hv; ol[o] = lv;
      }
    }
}

// O projection: o[8192][1024] x wo^T -> out = x + bo + acc   (out becomes x1)
__global__ __launch_bounds__(256) void k_oproj(const u16* __restrict__ oh, const u16* __restrict__ ol,
    const u16* __restrict__ wTh, const u16* __restrict__ wTl,
    const float* __restrict__ xin, const float* __restrict__ bo, float* __restrict__ outp)
{
  ACC_INIT4
  int m0 = blockIdx.y * 128, n0 = blockIdx.x * 128;
  gemm_core<128,0,3>(oh, ol, 1024, wTh, wTl, 1024, m0, n0, 1024, nullptr, 0, acc);
  EPI_COORDS(128)
  #pragma unroll
  for (int mi = 0; mi < 4; ++mi)
    #pragma unroll
    for (int i = 0; i < 4; ++i){
      size_t row = m0 + er0 + mi * 16 + i;
      #pragma unroll
      for (int nj = 0; nj < 4; ++nj){
        int cc = n0 + ec0 + nj * 16;
        size_t o = row * DD + cc;
        outp[o] = xin[o] + bo[cc] + acc[mi][nj][i];
      }
    }
}

// per-group compact offsets: base[e] = prefix of clamped counts within group of 4
__global__ void k_offsets(const int* __restrict__ cnt, int* __restrict__ base)
{
  if (threadIdx.x == 0 && blockIdx.x == 0){
    int b0 = 0, b1 = 0;
    for (int e = 0; e < 8; ++e){
      int c = cnt[e]; if (c > CAPC) c = CAPC;
      if (e < 4){ base[e] = b0; b0 += c; }
      else      { base[e] = b1; b1 += c; }
    }
  }
}

// MoE GEMM1 (merged over 4 experts): gathered split tokens x w1^T(bf16) -> relu -> h(bf16)
__global__ __launch_bounds__(256) void k_moe1_all(const u16* __restrict__ th, const u16* __restrict__ tl,
    const u16* __restrict__ w1T, const float* __restrict__ b1,
    const int* __restrict__ src, const int* __restrict__ cnt, const int* __restrict__ base,
    int g, u16* __restrict__ hbuf)
{
  const int z = blockIdx.z, eg = g * 4 + z;
  int c = cnt[eg]; if (c > CAPC) c = CAPC;
  const int m0 = blockIdx.y * 128;
  if (m0 >= c) return;
  const int n0 = blockIdx.x * 128;
  ACC_INIT4
  gemm_core<128,1,2>(th, tl, 1024, w1T + (size_t)z * FF * DD, nullptr, 1024,
                     m0, n0, 1024, src + eg * CAPC, c, acc);
  const float* b1e = b1 + (size_t)eg * FF;
  u16* hb = hbuf + (size_t)base[eg] * FF;
  EPI_COORDS(128)
  #pragma unroll
  for (int mi = 0; mi < 4; ++mi)
    #pragma unroll
    for (int i = 0; i < 4; ++i){
      int slot = m0 + er0 + mi * 16 + i;
      if (slot >= c) continue;
      #pragma unroll
      for (int nj = 0; nj < 4; ++nj){
        int cc = n0 + ec0 + nj * 16;
        hb[(size_t)slot * FF + cc] = f2bf(fmaxf(acc[mi][nj][i] + b1e[cc], 0.0f));
      }
    }
}

// MoE GEMM2 + combine (merged over 4 experts): h(bf16) x w2^T(bf16); out += g*(acc+b2)
__global__ __launch_bounds__(256) void k_moe2_all(const u16* __restrict__ hbuf,
    const u16* __restrict__ w2T, const float* __restrict__ b2,
    const int* __restrict__ src, const int* __restrict__ cnt, const int* __restrict__ base,
    int g, const float* __restrict__ gval, float* __restrict__ outp)
{
  const int z = blockIdx.z, eg = g * 4 + z;
  int c = cnt[eg]; if (c > CAPC) c = CAPC;
  const int m0 = blockIdx.y * 128;
  if (m0 >= c) return;
  const int n0 = blockIdx.x * 128;
  ACC_INIT4
  gemm_core<128,2,1>(hbuf + (size_t)base[eg] * FF, nullptr, FF,
                     w2T + (size_t)z * DD * FF, nullptr, FF,
                     m0, n0, FF, nullptr, c, acc);
  const float* b2e = b2 + (size_t)eg * DD;
  const int* srcp = src + eg * CAPC;
  EPI_COORDS(128)
  #pragma unroll
  for (int mi = 0; mi < 4; ++mi)
    #pragma unroll
    for (int i = 0; i < 4; ++i){
      int slot = m0 + er0 + mi * 16 + i;
      if (slot >= c) continue;
      int t = srcp[slot];
      float gv = gval[t];
      #pragma unroll
      for (int nj = 0; nj < 4; ++nj){
        int cc = n0 + ec0 + nj * 16;
        size_t o = (size_t)t * DD + cc;
        outp[o] += gv * (acc[mi][nj][i] + b2e[cc]);
      }
    }
}

// ===================================================================
// host side
// ===================================================================
static void old_attention(const float* x, const float* amask,
    const float* wq, const float* bq, const float* wk, const float* bk,
    const float* wv, const float* bv, const float* wo, const float* bo,
    const float* g1, const float* be1, float* stats1, float* x1f, char* A,
    hipStream_t stream)
{
  float* qc  = (float*)(A + 0);
  float* kc  = (float*)(A + 2097152);
  float* vc  = (float*)(A + 4194304);
  float* sc  = (float*)(A + 6291456);
  float* o_h = (float*)(A + 14680064);
  ln_stats<<<NTOK, 256, 0, stream>>>(x, stats1);
  init_x1<<<8192, 256, 0, stream>>>(x, bo, x1f);
  for (int h = 0; h < 16; ++h){
    int nofs = h * 64;
    proj_gemm<<<dim3(1, 128), 256, 0, stream>>>(x, stats1, g1, be1, wq, bq, 0.125f, nofs, qc);
    proj_gemm<<<dim3(1, 128), 256, 0, stream>>>(x, stats1, g1, be1, wk, bk, 1.0f,   nofs, kc);
    proj_gemm<<<dim3(1, 128), 256, 0, stream>>>(x, stats1, g1, be1, wv, bv, 1.0f,   nofs, vc);
    for (int qt = 0; qt < 4; ++qt){
      int pl0 = qt * 2;
      score_gemm<<<dim3(16, 16, 2), 256, 0, stream>>>(qc, kc, sc, pl0);
      softmax_io<<<2048, 256, 0, stream>>>(sc, amask);
      pv_gemm<<<dim3(1, 16, 2), 256, 0, stream>>>(sc, vc, o_h, pl0);
    }
    oproj_acc<<<dim3(16, 128), 256, 0, stream>>>(o_h, wo, h, x1f);
  }
}

extern "C" void kernel_launch(void* const* d_in, const int* in_sizes, int n_in,
                              void* d_out, int out_size, void* d_ws, size_t ws_size,
                              hipStream_t stream)
{
  (void)in_sizes; (void)n_in;
  const float* x     = (const float*)d_in[0];
  const float* amask = (const float*)d_in[1];
  const float* wq = (const float*)d_in[2];  const float* bq = (const float*)d_in[3];
  const float* wk = (const float*)d_in[4];  const float* bk = (const float*)d_in[5];
  const float* wv = (const float*)d_in[6];  const float* bv = (const float*)d_in[7];
  const float* wo = (const float*)d_in[8];  const float* bo = (const float*)d_in[9];
  const float* g1 = (const float*)d_in[10]; const float* be1 = (const float*)d_in[11];
  const float* g2 = (const float*)d_in[12]; const float* be2 = (const float*)d_in[13];
  const float* gw = (const float*)d_in[14];
  const float* w1 = (const float*)d_in[15]; const float* b1 = (const float*)d_in[16];
  const float* w2 = (const float*)d_in[17]; const float* b2 = (const float*)d_in[18];
  float* out = (float*)d_out;
  char* W = (char*)d_ws;
  const size_t MB = 1048576ull;

  // ---------------- Tier A ----------------
  if (ws_size >= 161 * MB){
    float* stats1 = (float*)(W + 0);
    float* stats2 = (float*)(W + 65536);
    float* logits = (float*)(W + 131072);
    float* gval   = (float*)(W + 393216);
    int*   src    = (int*)  (W + 425984);
    int*   cnt    = (int*)  (W + 557056);
    float* sums   = (float*)(W + 557312);
    int*   base   = (int*)  (W + 557568);

    // attention-phase layout
    u16* qh = (u16*)(W + 1*MB);   u16* ql = (u16*)(W + 17*MB);
    u16* kh = (u16*)(W + 33*MB);  u16* kl = (u16*)(W + 49*MB);
    u16* vh = (u16*)(W + 65*MB);  u16* vl = (u16*)(W + 81*MB);
    u16* xh = (u16*)(W + 97*MB);  u16* xl = (u16*)(W + 113*MB);
    u16* wTh = (u16*)(W + 129*MB); u16* wTl = (u16*)(W + 135*MB);  // 3072x1024 each (6 MB)
    u16* vTh = (u16*)(W + 97*MB);  u16* vTl = (u16*)(W + 113*MB);  // after xh/xl dead
    float* sc = (float*)(W + 65*MB);                                // 8-pair chunk, after v transposed
    u16* oh = (u16*)(W + 129*MB);  u16* ol = (u16*)(W + 145*MB);    // after wT dead
    u16* woTh = (u16*)(W + 65*MB); u16* woTl = (u16*)(W + 67*MB);   // after PV loop (sc dead)
    // MoE-phase layout
    u16* th  = qh;                 u16* tl  = ql;
    u16* w1T = (u16*)(W + 33*MB);                                   // 4 experts x [4096][1024]
    u16* w2T = (u16*)(W + 65*MB);                                   // 4 experts x [1024][4096]
    u16* hbuf= (u16*)(W + 97*MB);                                   // 8192 x 4096 bf16 (64 MB)

    hipMemsetAsync(cnt, 0, 512, stream);
    ln_stats<<<NTOK, 256, 0, stream>>>(x, stats1);
    k_ln_split<<<NTOK, 256, 0, stream>>>(x, stats1, g1, be1, xh, xl);

    // convert wq/wk/wv into contiguous [3072][1024] planes, one merged QKV GEMM
    k_split_T<<<dim3(16,16), 256, 0, stream>>>(wq, 1024, wTh,                wTl,                1024);
    k_split_T<<<dim3(16,16), 256, 0, stream>>>(wk, 1024, wTh + 1024*1024,    wTl + 1024*1024,    1024);
    k_split_T<<<dim3(16,16), 256, 0, stream>>>(wv, 1024, wTh + 2*1024*1024,  wTl + 2*1024*1024,  1024);
    k_proj_qkv<<<dim3(24,64), 256, 0, stream>>>(xh, xl, wTh, wTl, bq, bk, bv,
                                                qh, ql, kh, kl, vh, vl);
    k_transpose_bf<<<dim3(16,2,128), 256, 0, stream>>>(vh, vl, vTh, vTl);

    for (int pc = 0; pc < 16; ++pc){
      int pl0 = pc * 8;
      k_scores<<<dim3(8,8,8), 256, 0, stream>>>(qh, ql, kh, kl, amask, sc, pl0);
      k_softmax_ip<<<2048, 256, 0, stream>>>(sc);
      k_pv<<<dim3(1,8,8), 256, 0, stream>>>((const u16*)sc, vTh, vTl, oh, ol, pl0);
    }

    k_split_T<<<dim3(16,16), 256, 0, stream>>>(wo, 1024, woTh, woTl, 1024);
    k_oproj<<<dim3(8,64), 256, 0, stream>>>(oh, ol, woTh, woTl, x, bo, out);

    ln_stats<<<NTOK, 256, 0, stream>>>(out, stats2);
    logits_gemm<<<2048, 256, 0, stream>>>(out, stats2, g2, be2, gw, logits);
    routing_kernel<<<32, 256, 0, stream>>>(logits, gval, src, cnt, sums);
    laux_kernel<<<1, 64, 0, stream>>>(sums, cnt, out + (size_t)NTOK * DD);
    k_ln_split<<<NTOK, 256, 0, stream>>>(out, stats2, g2, be2, th, tl);
    k_offsets<<<1, 64, 0, stream>>>(cnt, base);

    for (int g = 0; g < 2; ++g){
      k_split_T1<<<dim3(64,16,4), 256, 0, stream>>>(w1 + (size_t)g*4*DD*FF, FF,
          w1T, DD, (size_t)DD*FF, (size_t)FF*DD);
      k_split_T1<<<dim3(16,64,4), 256, 0, stream>>>(w2 + (size_t)g*4*FF*DD, DD,
          w2T, FF, (size_t)FF*DD, (size_t)DD*FF);
      k_moe1_all<<<dim3(32,32,4), 256, 0, stream>>>(th, tl, w1T, b1, src, cnt, base, g, hbuf);
      k_moe2_all<<<dim3(8,32,4), 256, 0, stream>>>(hbuf, w2T, b2, src, cnt, base, g, gval, out);
    }
    return;
  }

  // ---------------- Tier C: fp32 fallback ----------------
  const size_t NEED = 51380224;
  if (ws_size < NEED){
    zerofill_kernel<<<(out_size + 255) / 256, 256, 0, stream>>>(out, out_size);
    return;
  }
  float* gval   = (float*)(W + 0);
  int*   src    = (int*)  (W + 32768);
  int*   cnt    = (int*)  (W + 163840);
  float* sums   = (float*)(W + 164096);
  float* stats1 = (float*)(W + 164352);
  float* stats2 = (float*)(W + 229888);
  float* logits = (float*)(W + 295424);
  float* x1f    = (float*)(W + 1048576);
  char* A = W + 1048576 + 33554432;
  float* hbuf = (float*)(A + 0);

  hipMemsetAsync(cnt, 0, 512, stream);
  old_attention(x, amask, wq, bq, wk, bk, wv, bv, wo, bo, g1, be1, stats1, x1f, A, stream);

  ln_stats<<<NTOK, 256, 0, stream>>>(x1f, stats2);
  logits_gemm<<<2048, 256, 0, stream>>>(x1f, stats2, g2, be2, gw, logits);
  routing_kernel<<<32, 256, 0, stream>>>(logits, gval, src, cnt, sums);
  laux_kernel<<<1, 64, 0, stream>>>(sums, cnt, out + (size_t)NTOK * DD);
  copy_x1<<<8192, 256, 0, stream>>>(x1f, out);

  for (int e = 0; e < 8; ++e){
    for (int ccn = 0; ccn < 4; ++ccn){
      int moff = ccn * 1024;
      moe1_gemm<<<dim3(64, 16), 256, 0, stream>>>(x1f, stats2, g2, be2,
          src + e * CAPC + moff, cnt + e, moff, w1 + (size_t)e * (DD * FF), b1 + (size_t)e * FF, hbuf);
      moe2_gemm<<<dim3(16, 16), 256, 0, stream>>>(hbuf, w2 + (size_t)e * (FF * DD),
          b2 + (size_t)e * DD, src + e * CAPC + moff, cnt + e, moff, gval, out);
    }
  }
}

// Round 4
// 1424.778 us; speedup vs baseline: 11.7493x; 1.4719x over previous
//
#include <hip/hip_runtime.h>

#define DD   1024
#define FF   4096
#define NTOK 8192
#define CAPC 4096

// ===================================================================
// Tier A (ws >= 161 MB, proven): split-bf16 MFMA pipeline.
//   - attention: fused flash kernel (causal-skipping, online softmax,
//     3-term Markidis split everywhere; P via XOR-swizzled LDS)
//   - MoE: bf16 weights/h (TERMS=2/1), experts merged per group of 4
// Tier C fallback: old fp32 kernel.
// ===================================================================

typedef unsigned short u16;
typedef __attribute__((ext_vector_type(8))) short bfrag;   // 8 bf16 = 4 VGPR
typedef __attribute__((ext_vector_type(4))) float f4_t;

#define MFMA(a,b,c) __builtin_amdgcn_mfma_f32_16x16x32_bf16(a,b,c,0,0,0)

__device__ __forceinline__ u16 f2bf(float f){
  unsigned u = __float_as_uint(f);
  u += 0x7FFFu + ((u >> 16) & 1u);          // RNE
  return (u16)(u >> 16);
}
__device__ __forceinline__ float bf2f(u16 h){
  return __uint_as_float(((unsigned)h) << 16);
}
__device__ __forceinline__ void bsplit(float v, u16& h, u16& l){
  h = f2bf(v);
  l = f2bf(v - bf2f(h));
}

__device__ __forceinline__ float block_sum(float v, float* sh){
  #pragma unroll
  for (int off = 32; off > 0; off >>= 1) v += __shfl_down(v, off, 64);
  if ((threadIdx.x & 63) == 0) sh[threadIdx.x >> 6] = v;
  __syncthreads();
  float r = (sh[0] + sh[1]) + (sh[2] + sh[3]);
  __syncthreads();
  return r;
}
__device__ __forceinline__ float block_max(float v, float* sh){
  #pragma unroll
  for (int off = 32; off > 0; off >>= 1) v = fmaxf(v, __shfl_down(v, off, 64));
  if ((threadIdx.x & 63) == 0) sh[threadIdx.x >> 6] = v;
  __syncthreads();
  float r = fmaxf(fmaxf(sh[0], sh[1]), fmaxf(sh[2], sh[3]));
  __syncthreads();
  return r;
}

// ============== old fp32 tile-GEMM core (Tier C fallback) ==============
#define GEMM_CORE(KTILES, LOADA, LOADB) \
  __shared__ float As[64][17]; \
  __shared__ float Bs[16][65]; \
  float cc_[4][4] = {{0,0,0,0},{0,0,0,0},{0,0,0,0},{0,0,0,0}}; \
  const int tx = threadIdx.x & 15, ty = threadIdx.x >> 4; \
  for (int kt = 0; kt < (KTILES); ++kt){ \
    _Pragma("unroll") \
    for (int q_ = 0; q_ < 4; ++q_){ \
      int id_ = q_ * 256 + threadIdx.x; \
      { int r_ = id_ >> 4; int k_ = kt * 16 + (id_ & 15); As[r_][id_ & 15] = (LOADA); } \
      { int c_ = id_ & 63; int k_ = kt * 16 + (id_ >> 6); Bs[id_ >> 6][c_] = (LOADB); } \
    } \
    __syncthreads(); \
    _Pragma("unroll") \
    for (int kk_ = 0; kk_ < 16; ++kk_){ \
      float a_[4], b_[4]; \
      _Pragma("unroll") \
      for (int i_ = 0; i_ < 4; ++i_) a_[i_] = As[ty * 4 + i_][kk_]; \
      _Pragma("unroll") \
      for (int j_ = 0; j_ < 4; ++j_) b_[j_] = Bs[kk_][tx * 4 + j_]; \
      _Pragma("unroll") \
      for (int i_ = 0; i_ < 4; ++i_) \
        _Pragma("unroll") \
        for (int j_ = 0; j_ < 4; ++j_) cc_[i_][j_] += a_[i_] * b_[j_]; \
    } \
    __syncthreads(); \
  }

__device__ __forceinline__ float ln_elem(const float* __restrict__ x, const float* __restrict__ st,
    const float* __restrict__ g, const float* __restrict__ be, int t, int k){
  return (x[(size_t)t * DD + k] - st[2 * t]) * st[2 * t + 1] * g[k] + be[k];
}

__global__ __launch_bounds__(256) void ln_stats(const float* __restrict__ xb, float* __restrict__ stats)
{
  __shared__ float sh[4];
  int n = blockIdx.x, tid = threadIdx.x;
  float4 xv = *(const float4*)(xb + (size_t)n * DD + tid * 4);
  float v[4] = { xv.x, xv.y, xv.z, xv.w };
  float s = (v[0] + v[1]) + (v[2] + v[3]);
  s = block_sum(s, sh);
  float m = s * (1.0f / DD);
  float q = 0;
  #pragma unroll
  for (int i = 0; i < 4; ++i){ float d = v[i] - m; q += d * d; }
  q = block_sum(q, sh);
  if (tid == 0){
    stats[2 * n]     = m;
    stats[2 * n + 1] = 1.0f / sqrtf(q * (1.0f / DD) + 1e-5f);
  }
}

__global__ __launch_bounds__(256) void init_x1(const float* __restrict__ x,
    const float* __restrict__ bo, float* __restrict__ x1f)
{
  size_t i = (size_t)blockIdx.x * 1024 + threadIdx.x * 4;
  float4 xv = *(const float4*)(x + i);
  float4 bv = *(const float4*)(bo + (i & (DD - 1)));
  xv.x += bv.x; xv.y += bv.y; xv.z += bv.z; xv.w += bv.w;
  *(float4*)(x1f + i) = xv;
}

__global__ __launch_bounds__(256) void proj_gemm(const float* __restrict__ xin,
    const float* __restrict__ st, const float* __restrict__ g, const float* __restrict__ be,
    const float* __restrict__ w, const float* __restrict__ bias, float escale, int nofs,
    float* __restrict__ outq)
{
  const int n0 = blockIdx.x * 64, m0 = blockIdx.y * 64;
  GEMM_CORE(64,
    (ln_elem(xin, st, g, be, m0 + r_, k_)),
    (w[(size_t)k_ * DD + nofs + n0 + c_]))
  #pragma unroll
  for (int i = 0; i < 4; ++i){
    int t = m0 + ty * 4 + i, s = t >> 3, b = t & 7;
    #pragma unroll
    for (int j = 0; j < 4; ++j){
      int col = n0 + tx * 4 + j;
      outq[(size_t)b * 65536 + (size_t)s * 64 + col] = (cc_[i][j] + bias[nofs + col]) * escale;
    }
  }
}

__global__ __launch_bounds__(256) void score_gemm(const float* __restrict__ qc,
    const float* __restrict__ kc, float* __restrict__ sc, int pl0)
{
  const int n0 = blockIdx.x * 64, m0 = blockIdx.y * 64, pz = blockIdx.z;
  const size_t pb = (size_t)(pl0 + pz) * 65536;
  GEMM_CORE(4,
    (qc[pb + (size_t)(m0 + r_) * 64 + k_]),
    (kc[pb + (size_t)(n0 + c_) * 64 + k_]))
  #pragma unroll
  for (int i = 0; i < 4; ++i){
    int row = m0 + ty * 4 + i;
    #pragma unroll
    for (int j = 0; j < 4; ++j)
      sc[(size_t)pz * 1048576 + (size_t)row * 1024 + n0 + tx * 4 + j] = cc_[i][j];
  }
}

__global__ __launch_bounds__(256) void softmax_io(float* __restrict__ sc, const float* __restrict__ mask)
{
  __shared__ float sh[4];
  int row = blockIdx.x, tid = threadIdx.x;
  int q = row & 1023;
  float* srow = sc + (size_t)row * 1024;
  const float* mrow = mask + (size_t)q * 1024;
  int j0 = tid * 4;
  float4 sv = *(const float4*)(srow + j0);
  float4 mv = *(const float4*)(mrow + j0);
  float v[4] = { sv.x + mv.x, sv.y + mv.y, sv.z + mv.z, sv.w + mv.w };
  float mx = fmaxf(fmaxf(v[0], v[1]), fmaxf(v[2], v[3]));
  mx = block_max(mx, sh);
  float e[4]; float l = 0;
  #pragma unroll
  for (int i = 0; i < 4; ++i){ e[i] = expf(v[i] - mx); l += e[i]; }
  l = block_sum(l, sh);
  float inv = 1.0f / l;
  #pragma unroll
  for (int i = 0; i < 4; ++i) srow[j0 + i] = e[i] * inv;
}

__global__ __launch_bounds__(256) void pv_gemm(const float* __restrict__ sc,
    const float* __restrict__ vc, float* __restrict__ o_h, int pl0)
{
  const int n0 = blockIdx.x * 64, m0 = blockIdx.y * 64, pz = blockIdx.z;
  const size_t pb = (size_t)(pl0 + pz) * 65536;
  GEMM_CORE(64,
    (sc[(size_t)pz * 1048576 + (size_t)(m0 + r_) * 1024 + k_]),
    (vc[pb + (size_t)k_ * 64 + n0 + c_]))
  int b = pl0 + pz;
  #pragma unroll
  for (int i = 0; i < 4; ++i){
    int s = m0 + ty * 4 + i;
    #pragma unroll
    for (int j = 0; j < 4; ++j)
      o_h[(size_t)b * 65536 + (size_t)s * 64 + n0 + tx * 4 + j] = cc_[i][j];
  }
}

__global__ __launch_bounds__(256) void oproj_acc(const float* __restrict__ o_h,
    const float* __restrict__ wo, int h, float* __restrict__ x1f)
{
  const int n0 = blockIdx.x * 64, m0 = blockIdx.y * 64;
  GEMM_CORE(4,
    (o_h[(size_t)((m0 + r_) & 7) * 65536 + (size_t)((m0 + r_) >> 3) * 64 + k_]),
    (wo[(size_t)(h * 64 + k_) * DD + n0 + c_]))
  #pragma unroll
  for (int i = 0; i < 4; ++i){
    size_t row = m0 + ty * 4 + i;
    #pragma unroll
    for (int j = 0; j < 4; ++j){
      size_t o = row * DD + n0 + tx * 4 + j;
      x1f[o] += cc_[i][j];
    }
  }
}

__global__ __launch_bounds__(256) void logits_gemm(const float* __restrict__ x1f,
    const float* __restrict__ st2, const float* __restrict__ g2, const float* __restrict__ be2,
    const float* __restrict__ gw, float* __restrict__ logits)
{
  int n = blockIdx.x * 4 + (threadIdx.x >> 6);
  int l = threadIdx.x & 63;
  float m = st2[2 * n], rs = st2[2 * n + 1];
  float acc[8] = {0,0,0,0,0,0,0,0};
  for (int i = 0; i < 16; ++i){
    int d = i * 64 + l;
    float t = (x1f[(size_t)n * DD + d] - m) * rs * g2[d] + be2[d];
    const float* gr = gw + (size_t)d * 8;
    #pragma unroll
    for (int e = 0; e < 8; ++e) acc[e] += t * gr[e];
  }
  #pragma unroll
  for (int e = 0; e < 8; ++e){
    #pragma unroll
    for (int off = 32; off > 0; off >>= 1) acc[e] += __shfl_down(acc[e], off, 64);
  }
  if (l == 0){
    #pragma unroll
    for (int e = 0; e < 8; ++e) logits[(size_t)n * 8 + e] = acc[e];
  }
}

__global__ void routing_kernel(const float* __restrict__ logits, float* __restrict__ gval,
    int* __restrict__ src, int* __restrict__ cnt, float* __restrict__ sums)
{
  int n = blockIdx.x * 256 + threadIdx.x;
  if (n >= NTOK) return;
  const float* L = logits + (size_t)n * 8;
  float l[8];
  #pragma unroll
  for (int e = 0; e < 8; ++e) l[e] = L[e];
  float best = l[0]; int be = 0;
  #pragma unroll
  for (int e = 1; e < 8; ++e) if (l[e] > best){ best = l[e]; be = e; }
  float g[8], es = 0;
  #pragma unroll
  for (int e = 0; e < 8; ++e){ g[e] = expf(l[e] - best); es += g[e]; }
  #pragma unroll
  for (int e = 0; e < 8; ++e) atomicAdd(&sums[e], g[e] / es);
  float gv = g[be] / es;
  int r = atomicAdd(&cnt[be], 1);
  bool keep = r < CAPC;
  gval[n] = keep ? gv : 0.0f;
  if (keep) src[be * CAPC + r] = n;
}

__global__ void laux_kernel(const float* __restrict__ sums, const int* __restrict__ cnt,
    float* __restrict__ outp)
{
  if (threadIdx.x == 0 && blockIdx.x == 0){
    float la = 0;
    for (int e = 0; e < 8; ++e) la += (sums[e] * (1.0f / NTOK)) * ((float)cnt[e] * (1.0f / NTOK));
    outp[0] = la * 8.0f;
  }
}

__global__ __launch_bounds__(256) void copy_x1(const float* __restrict__ x1f, float* __restrict__ outp)
{
  size_t i = (size_t)blockIdx.x * 1024 + threadIdx.x * 4;
  *(float4*)(outp + i) = *(const float4*)(x1f + i);
}

__global__ __launch_bounds__(256) void moe1_gemm(const float* __restrict__ x1f,
    const float* __restrict__ st2, const float* __restrict__ g2, const float* __restrict__ be2,
    const int* __restrict__ srcp, const int* __restrict__ cntp, int moff,
    const float* __restrict__ w1e, const float* __restrict__ b1e, float* __restrict__ hbuf)
{
  int c = *cntp; if (c > CAPC) c = CAPC; c -= moff; if (c < 0) c = 0;
  const int count = c < 1024 ? c : 1024;
  const int n0 = blockIdx.x * 64, m0 = blockIdx.y * 64;
  if (m0 >= count) return;
  GEMM_CORE(64,
    (ln_elem(x1f, st2, g2, be2, ((m0 + r_) < count ? srcp[m0 + r_] : 0), k_)),
    (w1e[(size_t)k_ * FF + n0 + c_]))
  #pragma unroll
  for (int i = 0; i < 4; ++i){
    int slot = m0 + ty * 4 + i;
    if (slot >= count) continue;
    #pragma unroll
    for (int j = 0; j < 4; ++j){
      int col = n0 + tx * 4 + j;
      hbuf[(size_t)slot * FF + col] = fmaxf(cc_[i][j] + b1e[col], 0.0f);
    }
  }
}

__global__ __launch_bounds__(256) void moe2_gemm(const float* __restrict__ hbuf,
    const float* __restrict__ w2e, const float* __restrict__ b2e, const int* __restrict__ srcp,
    const int* __restrict__ cntp, int moff, const float* __restrict__ gval,
    float* __restrict__ outp)
{
  int c = *cntp; if (c > CAPC) c = CAPC; c -= moff; if (c < 0) c = 0;
  const int count = c < 1024 ? c : 1024;
  const int n0 = blockIdx.x * 64, m0 = blockIdx.y * 64;
  if (m0 >= count) return;
  GEMM_CORE(256,
    (hbuf[(size_t)(m0 + r_) * FF + k_]),
    (w2e[(size_t)k_ * DD + n0 + c_]))
  #pragma unroll
  for (int i = 0; i < 4; ++i){
    int slot = m0 + ty * 4 + i;
    if (slot >= count) continue;
    int t = srcp[slot];
    float gv = gval[t];
    #pragma unroll
    for (int j = 0; j < 4; ++j){
      int col = n0 + tx * 4 + j;
      size_t o = (size_t)t * DD + col;
      outp[o] += gv * (cc_[i][j] + b2e[col]);
    }
  }
}

__global__ void zerofill_kernel(float* o, int nelem){
  int i = blockIdx.x * 256 + threadIdx.x;
  if (i < nelem) o[i] = 0.0f;
}

// ===================================================================
// unified split-bf16 MFMA GEMM core.  C = A * B^T.
// AMODE: 0 = direct rows, 1 = gather rows via srcp (clamped), 2 = clamp rows to count.
// TERMS: 3 = Ah*Bh+Ah*Bl+Al*Bh ; 2 = Ah*Bh+Al*Bh (B single plane) ; 1 = Ah*Bh.
// LDS rows padded to 40 u16 (80 B).
// ===================================================================
template<int BN, int AMODE, int TERMS>
__device__ __forceinline__ void gemm_core(
    const u16* __restrict__ Ah, const u16* __restrict__ Al, int lda,
    const u16* __restrict__ Bh, const u16* __restrict__ Bl, int ldb,
    int m0, int n0, int K, const int* __restrict__ srcp, int count,
    f4_t (&acc)[4][BN / 32])
{
  constexpr int NJ  = BN / 32;
  constexpr int LDP = 40;
  __shared__ u16 AsH[128 * LDP];
  __shared__ u16 AsL[(TERMS >= 2) ? 128 * LDP : LDP];
  __shared__ u16 BsH[BN * LDP];
  __shared__ u16 BsL[(TERMS >= 3) ? BN * LDP : LDP];
  const int tid = threadIdx.x;

  const int ar = tid >> 1;
  long arow;
  if constexpr (AMODE == 1){
    int r = m0 + ar; if (r >= count) r = (count > 0) ? count - 1 : 0;
    arow = srcp[r];
  } else if constexpr (AMODE == 2){
    int r = m0 + ar; if (r >= count) r = count - 1;
    arow = r;
  } else {
    arow = m0 + ar;
  }
  const size_t abase = (size_t)arow * lda + (size_t)((tid & 1) * 16);

  int br, boff;
  if constexpr (BN == 128){ br = tid >> 1; boff = (tid & 1) * 16; }
  else                    { br = tid >> 2; boff = (tid & 3) * 8; }
  const size_t bbase = (size_t)(n0 + br) * ldb + boff;

  u16* awh = &AsH[ar * LDP + (tid & 1) * 16];
  u16* awl = &AsL[(TERMS >= 2) ? (ar * LDP + (tid & 1) * 16) : 0];
  u16* bwh = &BsH[br * LDP + boff];
  u16* bwl = &BsL[(TERMS >= 3) ? (br * LDP + boff) : 0];

  uint4 rah0, rah1, ral0{}, ral1{}, rbh0, rbh1{}, rbl0{}, rbl1{};
  rah0 = *(const uint4*)(Ah + abase);  rah1 = *(const uint4*)(Ah + abase + 8);
  if constexpr (TERMS >= 2){ ral0 = *(const uint4*)(Al + abase); ral1 = *(const uint4*)(Al + abase + 8); }
  if constexpr (BN == 128){
    rbh0 = *(const uint4*)(Bh + bbase);  rbh1 = *(const uint4*)(Bh + bbase + 8);
    if constexpr (TERMS >= 3){ rbl0 = *(const uint4*)(Bl + bbase); rbl1 = *(const uint4*)(Bl + bbase + 8); }
  } else {
    rbh0 = *(const uint4*)(Bh + bbase);
    if constexpr (TERMS >= 3){ rbl0 = *(const uint4*)(Bl + bbase); }
  }

  const int KT = K >> 5;
  const int lane = tid & 63, wv = tid >> 6;
  const int wr = wv >> 1, wc = wv & 1;
  const int fr = lane & 15, fk = (lane >> 4) * 8;

  for (int kt = 0; kt < KT; ++kt){
    __syncthreads();
    *(uint4*)(awh) = rah0; *(uint4*)(awh + 8) = rah1;
    if constexpr (TERMS >= 2){ *(uint4*)(awl) = ral0; *(uint4*)(awl + 8) = ral1; }
    if constexpr (BN == 128){
      *(uint4*)(bwh) = rbh0; *(uint4*)(bwh + 8) = rbh1;
      if constexpr (TERMS >= 3){ *(uint4*)(bwl) = rbl0; *(uint4*)(bwl + 8) = rbl1; }
    } else {
      *(uint4*)(bwh) = rbh0;
      if constexpr (TERMS >= 3){ *(uint4*)(bwl) = rbl0; }
    }
    __syncthreads();
    if (kt + 1 < KT){
      const size_t a = abase + (size_t)(kt + 1) * 32;
      const size_t b = bbase + (size_t)(kt + 1) * 32;
      rah0 = *(const uint4*)(Ah + a); rah1 = *(const uint4*)(Ah + a + 8);
      if constexpr (TERMS >= 2){ ral0 = *(const uint4*)(Al + a); ral1 = *(const uint4*)(Al + a + 8); }
      if constexpr (BN == 128){
        rbh0 = *(const uint4*)(Bh + b); rbh1 = *(const uint4*)(Bh + b + 8);
        if constexpr (TERMS >= 3){ rbl0 = *(const uint4*)(Bl + b); rbl1 = *(const uint4*)(Bl + b + 8); }
      } else {
        rbh0 = *(const uint4*)(Bh + b);
        if constexpr (TERMS >= 3){ rbl0 = *(const uint4*)(Bl + b); }
      }
    }
    bfrag a_h[4], a_l[4];
    #pragma unroll
    for (int mi = 0; mi < 4; ++mi){
      int r = wr * 64 + mi * 16 + fr;
      a_h[mi] = *(const bfrag*)&AsH[r * LDP + fk];
      if constexpr (TERMS >= 2) a_l[mi] = *(const bfrag*)&AsL[r * LDP + fk];
    }
    #pragma unroll
    for (int nj = 0; nj < NJ; ++nj){
      int cidx = wc * (BN / 2) + nj * 16 + fr;
      bfrag b_h = *(const bfrag*)&BsH[cidx * LDP + fk];
      bfrag b_l;
      if constexpr (TERMS >= 3) b_l = *(const bfrag*)&BsL[cidx * LDP + fk];
      #pragma unroll
      for (int mi = 0; mi < 4; ++mi){
        acc[mi][nj] = MFMA(a_h[mi], b_h, acc[mi][nj]);
        if constexpr (TERMS >= 3) acc[mi][nj] = MFMA(a_h[mi], b_l, acc[mi][nj]);
        if constexpr (TERMS >= 2) acc[mi][nj] = MFMA(a_l[mi], b_h, acc[mi][nj]);
      }
    }
  }
}

#define EPI_COORDS(BNv) \
  const int lane_ = threadIdx.x & 63, wid_ = threadIdx.x >> 6; \
  const int er0 = (wid_ >> 1) * 64 + ((lane_ >> 4) << 2); \
  const int ec0 = (wid_ & 1) * ((BNv) / 2) + (lane_ & 15);

#define ACC_INIT4 \
  const f4_t fz_ = {0.f,0.f,0.f,0.f}; \
  f4_t acc[4][4]; \
  _Pragma("unroll") \
  for (int i_ = 0; i_ < 4; ++i_){ acc[i_][0]=fz_; acc[i_][1]=fz_; acc[i_][2]=fz_; acc[i_][3]=fz_; }

// ---------- conversion helpers ----------

__global__ __launch_bounds__(256) void k_ln_split(const float* __restrict__ xb,
    const float* __restrict__ st, const float* __restrict__ g, const float* __restrict__ be,
    u16* __restrict__ oh, u16* __restrict__ ol)
{
  int n = blockIdx.x, j = threadIdx.x * 4;
  float m = st[2 * n], rs = st[2 * n + 1];
  float4 xv = *(const float4*)(xb + (size_t)n * DD + j);
  float4 gv = *(const float4*)(g + j);
  float4 bv = *(const float4*)(be + j);
  float t0 = (xv.x - m) * rs * gv.x + bv.x;
  float t1 = (xv.y - m) * rs * gv.y + bv.y;
  float t2 = (xv.z - m) * rs * gv.z + bv.z;
  float t3 = (xv.w - m) * rs * gv.w + bv.w;
  ushort4 hv, lv;
  bsplit(t0, hv.x, lv.x); bsplit(t1, hv.y, lv.y);
  bsplit(t2, hv.z, lv.z); bsplit(t3, hv.w, lv.w);
  *(ushort4*)(oh + (size_t)n * DD + j) = hv;
  *(ushort4*)(ol + (size_t)n * DD + j) = lv;
}

__global__ __launch_bounds__(256) void k_split_T(const float* __restrict__ w, int ld,
    u16* __restrict__ th, u16* __restrict__ tl, int ldo)
{
  __shared__ float T[64][65];
  int n0 = blockIdx.x * 64, k0 = blockIdx.y * 64;
  int tx = threadIdx.x & 63, ty = threadIdx.x >> 6;
  #pragma unroll
  for (int r = 0; r < 16; ++r)
    T[ty * 16 + r][tx] = w[(size_t)(k0 + ty * 16 + r) * ld + n0 + tx];
  __syncthreads();
  #pragma unroll
  for (int r = 0; r < 16; ++r){
    int n = ty * 16 + r;
    float v = T[tx][n];
    u16 h, l; bsplit(v, h, l);
    size_t o = (size_t)(n0 + n) * ldo + k0 + tx;
    th[o] = h; tl[o] = l;
  }
}

__global__ __launch_bounds__(256) void k_split_T1(const float* __restrict__ w, int ld,
    u16* __restrict__ th, int ldo, size_t wstride, size_t ostride)
{
  __shared__ float T[64][65];
  const float* we = w + (size_t)blockIdx.z * wstride;
  u16* te = th + (size_t)blockIdx.z * ostride;
  int n0 = blockIdx.x * 64, k0 = blockIdx.y * 64;
  int tx = threadIdx.x & 63, ty = threadIdx.x >> 6;
  #pragma unroll
  for (int r = 0; r < 16; ++r)
    T[ty * 16 + r][tx] = we[(size_t)(k0 + ty * 16 + r) * ld + n0 + tx];
  __syncthreads();
  #pragma unroll
  for (int r = 0; r < 16; ++r){
    int n = ty * 16 + r;
    te[(size_t)(n0 + n) * ldo + k0 + tx] = f2bf(T[tx][n]);
  }
}

// bf16 planes [pair][1024][64] -> [pair][64][1024]  (V -> V^T)
__global__ __launch_bounds__(256) void k_transpose_bf(const u16* __restrict__ vh,
    const u16* __restrict__ vl, u16* __restrict__ vTh, u16* __restrict__ vTl)
{
  __shared__ u16 T[64][65];
  const u16* src = blockIdx.y ? vl : vh;
  u16* dst = blockIdx.y ? vTl : vTh;
  int pair = blockIdx.z, s0 = blockIdx.x * 64;
  src += (size_t)pair * 65536; dst += (size_t)pair * 65536;
  int tx = threadIdx.x & 63, ty = threadIdx.x >> 6;
  #pragma unroll
  for (int r = 0; r < 16; ++r)
    T[ty * 16 + r][tx] = src[(size_t)(s0 + ty * 16 + r) * 64 + tx];
  __syncthreads();
  #pragma unroll
  for (int r = 0; r < 16; ++r){
    int hd = ty * 16 + r;
    dst[(size_t)hd * 1024 + s0 + tx] = T[tx][hd];
  }
}

// ---------- MFMA GEMM wrappers ----------

// merged QKV projection with XCD-chunked swizzle
__global__ __launch_bounds__(256) void k_proj_qkv(const u16* __restrict__ xh, const u16* __restrict__ xl,
    const u16* __restrict__ wTh, const u16* __restrict__ wTl,
    const float* __restrict__ bq, const float* __restrict__ bk, const float* __restrict__ bv,
    u16* __restrict__ qh, u16* __restrict__ ql, u16* __restrict__ kh, u16* __restrict__ kl,
    u16* __restrict__ vh, u16* __restrict__ vl)
{
  ACC_INIT4
  // grid (24, 64): bijective XCD swizzle, 192 blocks per XCD = 8 m-bands x 24 n
  const int lin = blockIdx.y * 24 + blockIdx.x;
  const int id = (lin & 7) * 192 + (lin >> 3);
  const int n0 = (id % 24) * 128, m0 = (id / 24) * 128;
  gemm_core<128,0,3>(xh, xl, 1024, wTh, wTl, 1024, m0, n0, 1024, nullptr, 0, acc);
  const int sel = n0 >> 10;
  const float* bias = sel == 0 ? bq : (sel == 1 ? bk : bv);
  const float scale = sel == 0 ? 0.125f : 1.0f;
  u16* doh = sel == 0 ? qh : (sel == 1 ? kh : vh);
  u16* dol = sel == 0 ? ql : (sel == 1 ? kl : vl);
  const int nb = n0 & 1023;
  EPI_COORDS(128)
  #pragma unroll
  for (int mi = 0; mi < 4; ++mi){
    #pragma unroll
    for (int i = 0; i < 4; ++i){
      int t = m0 + er0 + mi * 16 + i;
      int s = t >> 3, b = t & 7;
      #pragma unroll
      for (int nj = 0; nj < 4; ++nj){
        int cc = nb + ec0 + nj * 16;
        float v = (acc[mi][nj][i] + bias[cc]) * scale;
        u16 hv, lv; bsplit(v, hv, lv);
        size_t o = (size_t)(b * 16 + (cc >> 6)) * 65536 + (size_t)s * 64 + (cc & 63);
        doh[o] = hv; dol[o] = lv;
      }
    }
  }
}

// ===================================================================
// fused flash attention (causal).  Block = (pair, q-tile of 128 rows).
// 4 waves, wave w owns q-rows [w*32, w*32+32).  No __syncthreads.
// Q,K: [pair][1024][64] split planes (Q pre-scaled by 1/8).
// vT:  [pair][64][1024] split planes.  out: oh/ol [tok][1024].
// P staged per-wave in XOR-swizzled LDS (16B-block swizzle, conflict-free).
// ===================================================================
__global__ __launch_bounds__(256, 2) void k_flash(
    const u16* __restrict__ qh, const u16* __restrict__ ql,
    const u16* __restrict__ kh, const u16* __restrict__ kl,
    const u16* __restrict__ vTh, const u16* __restrict__ vTl,
    u16* __restrict__ oh, u16* __restrict__ ol)
{
  __shared__ u16 Ph[4][32][128];   // 32 KB
  __shared__ u16 Pl[4][32][128];   // 32 KB
  // grid (128, 8); chunked swizzle: XCD k gets pairs [k*16, k*16+16), all q-tiles
  const int lin = blockIdx.y * 128 + blockIdx.x;
  const int id = (lin & 7) * 128 + (lin >> 3);
  const int pair = id >> 3, qt = id & 7;
  const int lane = threadIdx.x & 63, wid = threadIdx.x >> 6;
  const int fr = lane & 15, fg = lane >> 4;
  const size_t pb = (size_t)pair * 65536;

  // Q A-frags, kept in registers for all k-tiles
  bfrag qa_h[2][2], qa_l[2][2];
  #pragma unroll
  for (int mi = 0; mi < 2; ++mi){
    size_t ro = pb + (size_t)(qt * 128 + wid * 32 + mi * 16 + fr) * 64 + fg * 8;
    #pragma unroll
    for (int kk = 0; kk < 2; ++kk){
      qa_h[mi][kk] = *(const bfrag*)(qh + ro + kk * 32);
      qa_l[mi][kk] = *(const bfrag*)(ql + ro + kk * 32);
    }
  }

  const f4_t fz = {0.f, 0.f, 0.f, 0.f};
  f4_t O[2][4];
  #pragma unroll
  for (int mi = 0; mi < 2; ++mi){ O[mi][0]=fz; O[mi][1]=fz; O[mi][2]=fz; O[mi][3]=fz; }
  float mrow[2][4], lrow[2][4];
  #pragma unroll
  for (int mi = 0; mi < 2; ++mi)
    #pragma unroll
    for (int i = 0; i < 4; ++i){ mrow[mi][i] = -1e30f; lrow[mi][i] = 0.f; }

  for (int kt = 0; kt <= qt; ++kt){
    // ---- S = Q K^T : wave rows wid*32..+32, cols kt*128..+128 ----
    f4_t S[2][8];
    #pragma unroll
    for (int mi = 0; mi < 2; ++mi)
      #pragma unroll
      for (int nj = 0; nj < 8; ++nj) S[mi][nj] = fz;
    #pragma unroll
    for (int nj = 0; nj < 8; ++nj){
      size_t ko = pb + (size_t)(kt * 128 + nj * 16 + fr) * 64 + fg * 8;
      #pragma unroll
      for (int kk = 0; kk < 2; ++kk){
        bfrag bh = *(const bfrag*)(kh + ko + kk * 32);
        bfrag bl = *(const bfrag*)(kl + ko + kk * 32);
        #pragma unroll
        for (int mi = 0; mi < 2; ++mi){
          S[mi][nj] = MFMA(qa_h[mi][kk], bh, S[mi][nj]);
          S[mi][nj] = MFMA(qa_h[mi][kk], bl, S[mi][nj]);
          S[mi][nj] = MFMA(qa_l[mi][kk], bh, S[mi][nj]);
        }
      }
    }
    // ---- online softmax + P -> LDS (swizzled) ----
    const bool diag = (kt == qt);
    #pragma unroll
    for (int mi = 0; mi < 2; ++mi){
      #pragma unroll
      for (int i = 0; i < 4; ++i){
        const int rw = mi * 16 + fg * 4 + i;     // row within wave's 32
        const int lr = wid * 32 + rw;            // row within 128 q-tile
        float sv[8]; float mx = -1e30f;
        #pragma unroll
        for (int nj = 0; nj < 8; ++nj){
          float s = S[mi][nj][i];
          if (diag && (nj * 16 + fr) > lr) s = -1e30f;
          sv[nj] = s; mx = fmaxf(mx, s);
        }
        #pragma unroll
        for (int off = 1; off < 16; off <<= 1)
          mx = fmaxf(mx, __shfl_xor(mx, off, 64));
        float mold = mrow[mi][i];
        float mnew = fmaxf(mold, mx);
        float scl = __expf(mold - mnew);
        float ps = 0.f;
        #pragma unroll
        for (int nj = 0; nj < 8; ++nj){
          float p = __expf(sv[nj] - mnew);
          ps += p;
          u16 hv, lv; bsplit(p, hv, lv);
          int cidx = (((nj * 2 + (fr >> 3)) ^ (rw & 15)) << 3) + (fr & 7);
          Ph[wid][rw][cidx] = hv;
          Pl[wid][rw][cidx] = lv;
        }
        #pragma unroll
        for (int off = 1; off < 16; off <<= 1)
          ps += __shfl_xor(ps, off, 64);
        mrow[mi][i] = mnew;
        lrow[mi][i] = lrow[mi][i] * scl + ps;
        #pragma unroll
        for (int nj = 0; nj < 4; ++nj) O[mi][nj][i] *= scl;
      }
    }
    // ---- O += P V^T (wave-private LDS slice; compiler orders via lgkmcnt) ----
    #pragma unroll
    for (int ks = 0; ks < 4; ++ks){
      bfrag pa_h[2], pa_l[2];
      #pragma unroll
      for (int mi = 0; mi < 2; ++mi){
        int rw = mi * 16 + fr;
        int blk = (ks * 4 + fg) ^ (rw & 15);
        pa_h[mi] = *(const bfrag*)&Ph[wid][rw][blk << 3];
        pa_l[mi] = *(const bfrag*)&Pl[wid][rw][blk << 3];
      }
      #pragma unroll
      for (int nj = 0; nj < 4; ++nj){
        size_t vo = pb + (size_t)(nj * 16 + fr) * 1024 + kt * 128 + ks * 32 + fg * 8;
        bfrag vhf = *(const bfrag*)(vTh + vo);
        bfrag vlf = *(const bfrag*)(vTl + vo);
        #pragma unroll
        for (int mi = 0; mi < 2; ++mi){
          O[mi][nj] = MFMA(pa_h[mi], vhf, O[mi][nj]);
          O[mi][nj] = MFMA(pa_l[mi], vhf, O[mi][nj]);
          O[mi][nj] = MFMA(pa_h[mi], vlf, O[mi][nj]);
        }
      }
    }
  }
  // ---- normalize + split store ----
  const int b = pair >> 4, hh = pair & 15;
  #pragma unroll
  for (int mi = 0; mi < 2; ++mi){
    #pragma unroll
    for (int i = 0; i < 4; ++i){
      float inv = 1.0f / lrow[mi][i];
      int s = qt * 128 + wid * 32 + mi * 16 + fg * 4 + i;
      size_t t = (size_t)s * 8 + b;
      #pragma unroll
      for (int nj = 0; nj < 4; ++nj){
        u16 hv, lv; bsplit(O[mi][nj][i] * inv, hv, lv);
        size_t o = t * 1024 + hh * 64 + nj * 16 + fr;
        oh[o] = hv; ol[o] = lv;
      }
    }
  }
}

// O projection: o[8192][1024] x wo^T -> out = x + bo + acc   (out becomes x1)
__global__ __launch_bounds__(256) void k_oproj(const u16* __restrict__ oh, const u16* __restrict__ ol,
    const u16* __restrict__ wTh, const u16* __restrict__ wTl,
    const float* __restrict__ xin, const float* __restrict__ bo, float* __restrict__ outp)
{
  ACC_INIT4
  // grid (8, 64): XCD swizzle, 64 blocks per XCD = 8 m-bands x 8 n
  const int lin = blockIdx.y * 8 + blockIdx.x;
  const int id = (lin & 7) * 64 + (lin >> 3);
  const int n0 = (id & 7) * 128, m0 = (id >> 3) * 128;
  gemm_core<128,0,3>(oh, ol, 1024, wTh, wTl, 1024, m0, n0, 1024, nullptr, 0, acc);
  EPI_COORDS(128)
  #pragma unroll
  for (int mi = 0; mi < 4; ++mi)
    #pragma unroll
    for (int i = 0; i < 4; ++i){
      size_t row = m0 + er0 + mi * 16 + i;
      #pragma unroll
      for (int nj = 0; nj < 4; ++nj){
        int cc = n0 + ec0 + nj * 16;
        size_t o = row * DD + cc;
        outp[o] = xin[o] + bo[cc] + acc[mi][nj][i];
      }
    }
}

__global__ void k_offsets(const int* __restrict__ cnt, int* __restrict__ base)
{
  if (threadIdx.x == 0 && blockIdx.x == 0){
    int b0 = 0, b1 = 0;
    for (int e = 0; e < 8; ++e){
      int c = cnt[e]; if (c > CAPC) c = CAPC;
      if (e < 4){ base[e] = b0; b0 += c; }
      else      { base[e] = b1; b1 += c; }
    }
  }
}

__global__ __launch_bounds__(256) void k_moe1_all(const u16* __restrict__ th, const u16* __restrict__ tl,
    const u16* __restrict__ w1T, const float* __restrict__ b1,
    const int* __restrict__ src, const int* __restrict__ cnt, const int* __restrict__ base,
    int g, u16* __restrict__ hbuf)
{
  const int z = blockIdx.z, eg = g * 4 + z;
  int c = cnt[eg]; if (c > CAPC) c = CAPC;
  const int m0 = blockIdx.y * 128;
  if (m0 >= c) return;
  const int n0 = blockIdx.x * 128;
  ACC_INIT4
  gemm_core<128,1,2>(th, tl, 1024, w1T + (size_t)z * FF * DD, nullptr, 1024,
                     m0, n0, 1024, src + eg * CAPC, c, acc);
  const float* b1e = b1 + (size_t)eg * FF;
  u16* hb = hbuf + (size_t)base[eg] * FF;
  EPI_COORDS(128)
  #pragma unroll
  for (int mi = 0; mi < 4; ++mi)
    #pragma unroll
    for (int i = 0; i < 4; ++i){
      int slot = m0 + er0 + mi * 16 + i;
      if (slot >= c) continue;
      #pragma unroll
      for (int nj = 0; nj < 4; ++nj){
        int cc = n0 + ec0 + nj * 16;
        hb[(size_t)slot * FF + cc] = f2bf(fmaxf(acc[mi][nj][i] + b1e[cc], 0.0f));
      }
    }
}

__global__ __launch_bounds__(256) void k_moe2_all(const u16* __restrict__ hbuf,
    const u16* __restrict__ w2T, const float* __restrict__ b2,
    const int* __restrict__ src, const int* __restrict__ cnt, const int* __restrict__ base,
    int g, const float* __restrict__ gval, float* __restrict__ outp)
{
  const int z = blockIdx.z, eg = g * 4 + z;
  int c = cnt[eg]; if (c > CAPC) c = CAPC;
  const int m0 = blockIdx.y * 128;
  if (m0 >= c) return;
  const int n0 = blockIdx.x * 128;
  ACC_INIT4
  gemm_core<128,2,1>(hbuf + (size_t)base[eg] * FF, nullptr, FF,
                     w2T + (size_t)z * DD * FF, nullptr, FF,
                     m0, n0, FF, nullptr, c, acc);
  const float* b2e = b2 + (size_t)eg * DD;
  const int* srcp = src + eg * CAPC;
  EPI_COORDS(128)
  #pragma unroll
  for (int mi = 0; mi < 4; ++mi)
    #pragma unroll
    for (int i = 0; i < 4; ++i){
      int slot = m0 + er0 + mi * 16 + i;
      if (slot >= c) continue;
      int t = srcp[slot];
      float gv = gval[t];
      #pragma unroll
      for (int nj = 0; nj < 4; ++nj){
        int cc = n0 + ec0 + nj * 16;
        size_t o = (size_t)t * DD + cc;
        outp[o] += gv * (acc[mi][nj][i] + b2e[cc]);
      }
    }
}

// ===================================================================
// host side
// ===================================================================
static void old_attention(const float* x, const float* amask,
    const float* wq, const float* bq, const float* wk, const float* bk,
    const float* wv, const float* bv, const float* wo, const float* bo,
    const float* g1, const float* be1, float* stats1, float* x1f, char* A,
    hipStream_t stream)
{
  float* qc  = (float*)(A + 0);
  float* kc  = (float*)(A + 2097152);
  float* vc  = (float*)(A + 4194304);
  float* sc  = (float*)(A + 6291456);
  float* o_h = (float*)(A + 14680064);
  ln_stats<<<NTOK, 256, 0, stream>>>(x, stats1);
  init_x1<<<8192, 256, 0, stream>>>(x, bo, x1f);
  for (int h = 0; h < 16; ++h){
    int nofs = h * 64;
    proj_gemm<<<dim3(1, 128), 256, 0, stream>>>(x, stats1, g1, be1, wq, bq, 0.125f, nofs, qc);
    proj_gemm<<<dim3(1, 128), 256, 0, stream>>>(x, stats1, g1, be1, wk, bk, 1.0f,   nofs, kc);
    proj_gemm<<<dim3(1, 128), 256, 0, stream>>>(x, stats1, g1, be1, wv, bv, 1.0f,   nofs, vc);
    for (int qt = 0; qt < 4; ++qt){
      int pl0 = qt * 2;
      score_gemm<<<dim3(16, 16, 2), 256, 0, stream>>>(qc, kc, sc, pl0);
      softmax_io<<<2048, 256, 0, stream>>>(sc, amask);
      pv_gemm<<<dim3(1, 16, 2), 256, 0, stream>>>(sc, vc, o_h, pl0);
    }
    oproj_acc<<<dim3(16, 128), 256, 0, stream>>>(o_h, wo, h, x1f);
  }
}

extern "C" void kernel_launch(void* const* d_in, const int* in_sizes, int n_in,
                              void* d_out, int out_size, void* d_ws, size_t ws_size,
                              hipStream_t stream)
{
  (void)in_sizes; (void)n_in;
  const float* x     = (const float*)d_in[0];
  const float* amask = (const float*)d_in[1];
  const float* wq = (const float*)d_in[2];  const float* bq = (const float*)d_in[3];
  const float* wk = (const float*)d_in[4];  const float* bk = (const float*)d_in[5];
  const float* wv = (const float*)d_in[6];  const float* bv = (const float*)d_in[7];
  const float* wo = (const float*)d_in[8];  const float* bo = (const float*)d_in[9];
  const float* g1 = (const float*)d_in[10]; const float* be1 = (const float*)d_in[11];
  const float* g2 = (const float*)d_in[12]; const float* be2 = (const float*)d_in[13];
  const float* gw = (const float*)d_in[14];
  const float* w1 = (const float*)d_in[15]; const float* b1 = (const float*)d_in[16];
  const float* w2 = (const float*)d_in[17]; const float* b2 = (const float*)d_in[18];
  float* out = (float*)d_out;
  char* W = (char*)d_ws;
  const size_t MB = 1048576ull;

  // ---------------- Tier A ----------------
  if (ws_size >= 161 * MB){
    float* stats1 = (float*)(W + 0);
    float* stats2 = (float*)(W + 65536);
    float* logits = (float*)(W + 131072);
    float* gval   = (float*)(W + 393216);
    int*   src    = (int*)  (W + 425984);
    int*   cnt    = (int*)  (W + 557056);
    float* sums   = (float*)(W + 557312);
    int*   base   = (int*)  (W + 557568);

    // attention-phase layout
    u16* qh = (u16*)(W + 1*MB);   u16* ql = (u16*)(W + 17*MB);
    u16* kh = (u16*)(W + 33*MB);  u16* kl = (u16*)(W + 49*MB);
    u16* vh = (u16*)(W + 65*MB);  u16* vl = (u16*)(W + 81*MB);
    u16* xh = (u16*)(W + 97*MB);  u16* xl = (u16*)(W + 113*MB);
    u16* wTh = (u16*)(W + 129*MB); u16* wTl = (u16*)(W + 135*MB);  // 3072x1024 each (6 MB)
    u16* vTh = (u16*)(W + 97*MB);  u16* vTl = (u16*)(W + 113*MB);  // after xh/xl dead
    u16* oh = (u16*)(W + 129*MB);  u16* ol = (u16*)(W + 145*MB);   // after wT dead
    u16* woTh = (u16*)(W + 65*MB); u16* woTl = (u16*)(W + 67*MB);  // after vh/vl dead
    // MoE-phase layout
    u16* th  = qh;                 u16* tl  = ql;
    u16* w1T = (u16*)(W + 33*MB);                                  // 4 experts x [4096][1024]
    u16* w2T = (u16*)(W + 65*MB);                                  // 4 experts x [1024][4096]
    u16* hbuf= (u16*)(W + 97*MB);                                  // 8192 x 4096 bf16 (64 MB)

    hipMemsetAsync(cnt, 0, 512, stream);
    ln_stats<<<NTOK, 256, 0, stream>>>(x, stats1);
    k_ln_split<<<NTOK, 256, 0, stream>>>(x, stats1, g1, be1, xh, xl);

    k_split_T<<<dim3(16,16), 256, 0, stream>>>(wq, 1024, wTh,                wTl,                1024);
    k_split_T<<<dim3(16,16), 256, 0, stream>>>(wk, 1024, wTh + 1024*1024,    wTl + 1024*1024,    1024);
    k_split_T<<<dim3(16,16), 256, 0, stream>>>(wv, 1024, wTh + 2*1024*1024,  wTl + 2*1024*1024,  1024);
    k_proj_qkv<<<dim3(24,64), 256, 0, stream>>>(xh, xl, wTh, wTl, bq, bk, bv,
                                                qh, ql, kh, kl, vh, vl);
    k_transpose_bf<<<dim3(16,2,128), 256, 0, stream>>>(vh, vl, vTh, vTl);

    // fused flash attention: one launch, 1024 blocks
    k_flash<<<dim3(128, 8), 256, 0, stream>>>(qh, ql, kh, kl, vTh, vTl, oh, ol);

    k_split_T<<<dim3(16,16), 256, 0, stream>>>(wo, 1024, woTh, woTl, 1024);
    k_oproj<<<dim3(8,64), 256, 0, stream>>>(oh, ol, woTh, woTl, x, bo, out);

    ln_stats<<<NTOK, 256, 0, stream>>>(out, stats2);
    logits_gemm<<<2048, 256, 0, stream>>>(out, stats2, g2, be2, gw, logits);
    routing_kernel<<<32, 256, 0, stream>>>(logits, gval, src, cnt, sums);
    laux_kernel<<<1, 64, 0, stream>>>(sums, cnt, out + (size_t)NTOK * DD);
    k_ln_split<<<NTOK, 256, 0, stream>>>(out, stats2, g2, be2, th, tl);
    k_offsets<<<1, 64, 0, stream>>>(cnt, base);

    for (int g = 0; g < 2; ++g){
      k_split_T1<<<dim3(64,16,4), 256, 0, stream>>>(w1 + (size_t)g*4*DD*FF, FF,
          w1T, DD, (size_t)DD*FF, (size_t)FF*DD);
      k_split_T1<<<dim3(16,64,4), 256, 0, stream>>>(w2 + (size_t)g*4*FF*DD, DD,
          w2T, FF, (size_t)FF*DD, (size_t)DD*FF);
      k_moe1_all<<<dim3(32,32,4), 256, 0, stream>>>(th, tl, w1T, b1, src, cnt, base, g, hbuf);
      k_moe2_all<<<dim3(8,32,4), 256, 0, stream>>>(hbuf, w2T, b2, src, cnt, base, g, gval, out);
    }
    return;
  }

  // ---------------- Tier C: fp32 fallback ----------------
  const size_t NEED = 51380224;
  if (ws_size < NEED){
    zerofill_kernel<<<(out_size + 255) / 256, 256, 0, stream>>>(out, out_size);
    return;
  }
  float* gval   = (float*)(W + 0);
  int*   src    = (int*)  (W + 32768);
  int*   cnt    = (int*)  (W + 163840);
  float* sums   = (float*)(W + 164096);
  float* stats1 = (float*)(W + 164352);
  float* stats2 = (float*)(W + 229888);
  float* logits = (float*)(W + 295424);
  float* x1f    = (float*)(W + 1048576);
  char* A = W + 1048576 + 33554432;
  float* hbuf = (float*)(A + 0);

  hipMemsetAsync(cnt, 0, 512, stream);
  old_attention(x, amask, wq, bq, wk, bk, wv, bv, wo, bo, g1, be1, stats1, x1f, A, stream);

  ln_stats<<<NTOK, 256, 0, stream>>>(x1f, stats2);
  logits_gemm<<<2048, 256, 0, stream>>>(x1f, stats2, g2, be2, gw, logits);
  routing_kernel<<<32, 256, 0, stream>>>(logits, gval, src, cnt, sums);
  laux_kernel<<<1, 64, 0, stream>>>(sums, cnt, out + (size_t)NTOK * DD);
  copy_x1<<<8192, 256, 0, stream>>>(x1f, out);

  for (int e = 0; e < 8; ++e){
    for (int ccn = 0; ccn < 4; ++ccn){
      int moff = ccn * 1024;
      moe1_gemm<<<dim3(64, 16), 256, 0, stream>>>(x1f, stats2, g2, be2,
          src + e * CAPC + moff, cnt + e, moff, w1 + (size_t)e * (DD * FF), b1 + (size_t)e * FF, hbuf);
      moe2_gemm<<<dim3(16, 16), 256, 0, stream>>>(hbuf, w2 + (size_t)e * (FF * DD),
          b2 + (size_t)e * DD, src + e * CAPC + moff, cnt + e, moff, gval, out);
    }
  }
}